// Round 1
// baseline (711.315 us; speedup 1.0000x reference)
//
#include <hip/hip_runtime.h>
#include <math.h>

// ---------------------------------------------------------------------------
// GAT pipeline:
//   CSR build (count -> scan -> scatter)   [once per launch, inputs re-poisoned]
//   per layer: fp32 tiled GEMM -> per-node attention stats -> wave-per-node agg
//   mean pool -> 2-layer MLP -> scalar out
// ---------------------------------------------------------------------------

// ---------------- CSR build ----------------
__global__ void count_kernel(const int* __restrict__ ei, int* __restrict__ counts,
                             int E, int n) {
  int t = blockIdx.x * blockDim.x + threadIdx.x;
  if (t < E) {
    atomicAdd(&counts[ei[E + t]], 1);          // dst row of edge_index
  } else if (t < E + n) {
    atomicAdd(&counts[t - E], 1);              // self loop
  }
}

__global__ void scan_kernel(const int* __restrict__ counts, int* __restrict__ offsets,
                            int n) {
  __shared__ int sd[1024];
  __shared__ int carry_sh;
  int tid = threadIdx.x;
  if (tid == 0) carry_sh = 0;
  __syncthreads();
  for (int base = 0; base < n; base += 1024) {
    int i = base + tid;
    int v = (i < n) ? counts[i] : 0;
    sd[tid] = v;
    __syncthreads();
    for (int off = 1; off < 1024; off <<= 1) {
      int t = (tid >= off) ? sd[tid - off] : 0;
      __syncthreads();
      sd[tid] += t;
      __syncthreads();
    }
    int carry = carry_sh;
    if (i < n) offsets[i] = carry + sd[tid] - v;   // exclusive scan
    __syncthreads();
    if (tid == 1023) carry_sh = carry + sd[1023];
    __syncthreads();
  }
  if (tid == 0) offsets[n] = carry_sh;
}

__global__ void scatter_kernel(const int* __restrict__ ei, const int* __restrict__ offsets,
                               int* __restrict__ cursor, int* __restrict__ srcs,
                               int E, int n) {
  int t = blockIdx.x * blockDim.x + threadIdx.x;
  int s, d;
  if (t < E)          { s = ei[t]; d = ei[E + t]; }
  else if (t < E + n) { s = t - E; d = s; }
  else return;
  int pos = offsets[d] + atomicAdd(&cursor[d], 1);
  srcs[pos] = s;
}

// ---------------- fp32 tiled GEMM: C[M,N] = A[M,K] @ B[K,N] ----------------
// BM=BN=64, BK=16, 256 threads, 4x4 per thread. K % 16 == 0, N % 64 == 0.
__global__ __launch_bounds__(256) void gemm_kernel(
    const float* __restrict__ A, const float* __restrict__ B, float* __restrict__ C,
    int M, int K, int N) {
  __shared__ float As[16][64 + 4];   // +4 pad keeps ds_read_b128 alignment
  __shared__ float Bs[16][64];
  int tid = threadIdx.x;
  int tx = tid & 15, ty = tid >> 4;
  int row0 = blockIdx.y * 64, col0 = blockIdx.x * 64;
  int ar = tid >> 2, ak = (tid & 3) << 2;      // A: 64 rows x 16 k, float4/thread
  int bk = tid >> 4, bn = (tid & 15) << 2;     // B: 16 k x 64 cols, float4/thread
  float acc[4][4] = {};
  for (int k0 = 0; k0 < K; k0 += 16) {
    float4 av = make_float4(0.f, 0.f, 0.f, 0.f);
    if (row0 + ar < M)
      av = *(const float4*)(A + (size_t)(row0 + ar) * K + k0 + ak);
    As[ak + 0][ar] = av.x; As[ak + 1][ar] = av.y;
    As[ak + 2][ar] = av.z; As[ak + 3][ar] = av.w;
    float4 bv = *(const float4*)(B + (size_t)(k0 + bk) * N + col0 + bn);
    *(float4*)&Bs[bk][bn] = bv;
    __syncthreads();
#pragma unroll
    for (int kk = 0; kk < 16; ++kk) {
      float a0 = As[kk][ty * 4 + 0], a1 = As[kk][ty * 4 + 1];
      float a2 = As[kk][ty * 4 + 2], a3 = As[kk][ty * 4 + 3];
      float b0 = Bs[kk][tx * 4 + 0], b1 = Bs[kk][tx * 4 + 1];
      float b2 = Bs[kk][tx * 4 + 2], b3 = Bs[kk][tx * 4 + 3];
      acc[0][0] += a0 * b0; acc[0][1] += a0 * b1; acc[0][2] += a0 * b2; acc[0][3] += a0 * b3;
      acc[1][0] += a1 * b0; acc[1][1] += a1 * b1; acc[1][2] += a1 * b2; acc[1][3] += a1 * b3;
      acc[2][0] += a2 * b0; acc[2][1] += a2 * b1; acc[2][2] += a2 * b2; acc[2][3] += a2 * b3;
      acc[3][0] += a3 * b0; acc[3][1] += a3 * b1; acc[3][2] += a3 * b2; acc[3][3] += a3 * b3;
    }
    __syncthreads();
  }
#pragma unroll
  for (int i = 0; i < 4; ++i) {
    int row = row0 + ty * 4 + i;
    if (row < M) {
      float4 v = make_float4(acc[i][0], acc[i][1], acc[i][2], acc[i][3]);
      *(float4*)(C + (size_t)row * N + col0 + tx * 4) = v;
    }
  }
}

// ---------------- per-node attention stats: asn/adn[n,h] = <xl[n,h,:], a_{s,d}[h,:]>
template <int H>
__global__ __launch_bounds__(256) void stat_kernel(
    const float* __restrict__ xl, const float* __restrict__ a_s,
    const float* __restrict__ a_d, float* __restrict__ asn, float* __restrict__ adn,
    int n) {
  int wid = (blockIdx.x * blockDim.x + threadIdx.x) >> 6;
  int lane = threadIdx.x & 63;
  if (wid >= n) return;
  const float* row = xl + (size_t)wid * (H * 128);
#pragma unroll
  for (int h = 0; h < H; ++h) {
    float v0 = row[h * 128 + lane], v1 = row[h * 128 + 64 + lane];
    float ps = v0 * a_s[h * 128 + lane] + v1 * a_s[h * 128 + 64 + lane];
    float pd = v0 * a_d[h * 128 + lane] + v1 * a_d[h * 128 + 64 + lane];
    for (int m = 32; m; m >>= 1) {
      ps += __shfl_xor(ps, m);
      pd += __shfl_xor(pd, m);
    }
    if (lane == 0) { asn[wid * H + h] = ps; adn[wid * H + h] = pd; }
  }
}

// ---------------- wave-per-node softmax + aggregation ----------------
template <int H, bool RELU>
__global__ __launch_bounds__(256) void agg_kernel(
    const float* __restrict__ xl, const float* __restrict__ asn,
    const float* __restrict__ adn, const int* __restrict__ offsets,
    const int* __restrict__ srcs, const float* __restrict__ bias,
    float* __restrict__ out, int n) {
  constexpr int C = 128;
  constexpr int HC = H * C;
  constexpr int CPL = HC / 64;        // channels per lane: 8 (H=4) or 2 (H=1)
  __shared__ float alpha_sh[4][64 * H];
  __shared__ int src_sh[4][64];
  int wib = threadIdx.x >> 6;
  int lane = threadIdx.x & 63;
  int nd = blockIdx.x * 4 + wib;
  if (nd >= n) return;
  int beg = offsets[nd];
  int deg = offsets[nd + 1] - beg;
  float adl[H];
#pragma unroll
  for (int h = 0; h < H; ++h) adl[h] = adn[nd * H + h];

  // pass 1: per-head max of leaky_relu(asn[src]+adn[dst])
  float mh[H];
#pragma unroll
  for (int h = 0; h < H; ++h) mh[h] = -3.0e38f;
  for (int j0 = 0; j0 < deg; j0 += 64) {
    int j = j0 + lane;
    if (j < deg) {
      int s = srcs[beg + j];
#pragma unroll
      for (int h = 0; h < H; ++h) {
        float e = asn[s * H + h] + adl[h];
        e = (e > 0.f) ? e : 0.2f * e;
        mh[h] = fmaxf(mh[h], e);
      }
    }
  }
#pragma unroll
  for (int h = 0; h < H; ++h)
    for (int m = 32; m; m >>= 1) mh[h] = fmaxf(mh[h], __shfl_xor(mh[h], m));

  // pass 2: denominators
  float den[H];
#pragma unroll
  for (int h = 0; h < H; ++h) den[h] = 0.f;
  for (int j0 = 0; j0 < deg; j0 += 64) {
    int j = j0 + lane;
    if (j < deg) {
      int s = srcs[beg + j];
#pragma unroll
      for (int h = 0; h < H; ++h) {
        float e = asn[s * H + h] + adl[h];
        e = (e > 0.f) ? e : 0.2f * e;
        den[h] += expf(e - mh[h]);
      }
    }
  }
#pragma unroll
  for (int h = 0; h < H; ++h) {
    for (int m = 32; m; m >>= 1) den[h] += __shfl_xor(den[h], m);
    den[h] = 1.f / den[h];             // now holds 1/den
  }

  // pass 3: out[nd] = sum_j alpha_j * xl[src_j]
  float acc[CPL];
#pragma unroll
  for (int i = 0; i < CPL; ++i) acc[i] = 0.f;
  int ch0 = lane * CPL;
  int hm = ch0 / C;                    // my head
  for (int j0 = 0; j0 < deg; j0 += 64) {
    int j = j0 + lane;
    if (j < deg) {
      int s = srcs[beg + j];
      src_sh[wib][lane] = s;
#pragma unroll
      for (int h = 0; h < H; ++h) {
        float e = asn[s * H + h] + adl[h];
        e = (e > 0.f) ? e : 0.2f * e;
        alpha_sh[wib][lane * H + h] = expf(e - mh[h]) * den[h];
      }
    }
    __builtin_amdgcn_wave_barrier();   // wave-lockstep LDS producer->consumer
    int cl = min(64, deg - j0);
    for (int jj = 0; jj < cl; ++jj) {
      int s = src_sh[wib][jj];
      float a = alpha_sh[wib][jj * H + hm];
      const float* p = xl + (size_t)s * HC + ch0;
      if constexpr (CPL == 8) {
        float4 v0 = *(const float4*)p;
        float4 v1 = *(const float4*)(p + 4);
        acc[0] += a * v0.x; acc[1] += a * v0.y; acc[2] += a * v0.z; acc[3] += a * v0.w;
        acc[4] += a * v1.x; acc[5] += a * v1.y; acc[6] += a * v1.z; acc[7] += a * v1.w;
      } else {
        float2 v = *(const float2*)p;
        acc[0] += a * v.x; acc[1] += a * v.y;
      }
    }
    __builtin_amdgcn_wave_barrier();
  }
  float* op = out + (size_t)nd * HC + ch0;
#pragma unroll
  for (int i = 0; i < CPL; ++i) {
    float v = acc[i] + bias[ch0 + i];
    if (RELU) v = fmaxf(v, 0.f);
    op[i] = v;
  }
}

// ---------------- mean pool (partial sums + atomics) ----------------
__global__ void pool_kernel(const float* __restrict__ h, float* __restrict__ g, int n) {
  int c = threadIdx.x;                 // 128 threads
  float acc = 0.f;
  for (int r = blockIdx.x; r < n; r += gridDim.x) acc += h[(size_t)r * 128 + c];
  atomicAdd(&g[c], acc);
}

// ---------------- final MLP: relu(g/N @ Wm1 + bm1) @ Wm2 + bm2 ----------------
__global__ void mlp_kernel(const float* __restrict__ g, const float* __restrict__ Wm1,
                           const float* __restrict__ bm1, const float* __restrict__ Wm2,
                           const float* __restrict__ bm2, float* __restrict__ out,
                           float invn) {
  __shared__ float gs[128];
  __shared__ float hs[64];
  int t = threadIdx.x;                 // 64 threads
  gs[t] = g[t] * invn;
  gs[t + 64] = g[t + 64] * invn;
  __syncthreads();
  float acc = bm1[t];
  for (int c = 0; c < 128; ++c) acc += gs[c] * Wm1[c * 64 + t];
  hs[t] = fmaxf(acc, 0.f);
  __syncthreads();
  if (t == 0) {
    float o = bm2[0];
    for (int j = 0; j < 64; ++j) o += hs[j] * Wm2[j];
    out[0] = o;
  }
}

// ---------------------------------------------------------------------------
extern "C" void kernel_launch(void* const* d_in, const int* in_sizes, int n_in,
                              void* d_out, int out_size, void* d_ws, size_t ws_size,
                              hipStream_t stream) {
  const float* x   = (const float*)d_in[0];
  const int*   ei  = (const int*)d_in[1];
  const float* W0  = (const float*)d_in[2];
  const float* as0 = (const float*)d_in[3];
  const float* ad0 = (const float*)d_in[4];
  const float* b0  = (const float*)d_in[5];
  const float* W1  = (const float*)d_in[6];
  const float* as1 = (const float*)d_in[7];
  const float* ad1 = (const float*)d_in[8];
  const float* b1  = (const float*)d_in[9];
  const float* W2  = (const float*)d_in[10];
  const float* as2 = (const float*)d_in[11];
  const float* ad2 = (const float*)d_in[12];
  const float* b2  = (const float*)d_in[13];
  const float* Wm1 = (const float*)d_in[14];
  const float* bm1 = (const float*)d_in[15];
  const float* Wm2 = (const float*)d_in[16];
  const float* bm2 = (const float*)d_in[17];

  const int N = in_sizes[0] / 128;     // 20000
  const int E = in_sizes[1] / 2;       // 320000
  const int ET = E + N;                // with self loops

  // workspace layout (fp32 words)
  float* A    = (float*)d_ws;               // N*512  (xl of current layer; L2 out at +N*128)
  float* Bb   = A + (size_t)N * 512;        // N*512  (h between layers)
  float* asn  = Bb + (size_t)N * 512;       // N*4
  float* adn  = asn + (size_t)N * 4;        // N*4
  float* g    = adn + (size_t)N * 4;        // 128 pool accumulator
  int* counts = (int*)(g + 128);            // N
  int* cursor = counts + N;                 // N
  int* offs   = cursor + N;                 // N+1
  int* srcs   = offs + N + 1;               // ET

  // zero pool accumulator + counts + cursor (contiguous)
  hipMemsetAsync(g, 0, (size_t)(128 + 2 * N) * sizeof(int), stream);

  // CSR by dst
  int ebl = (ET + 255) / 256;
  count_kernel<<<ebl, 256, 0, stream>>>(ei, counts, E, N);
  scan_kernel<<<1, 1024, 0, stream>>>(counts, offs, N);
  scatter_kernel<<<ebl, 256, 0, stream>>>(ei, offs, cursor, srcs, E, N);

  int nwb = (N + 3) / 4;               // wave-per-node kernels: 4 waves/block
  dim3 gL01((512 + 63) / 64, (N + 63) / 64);
  dim3 gL2((128 + 63) / 64, (N + 63) / 64);

  // layer 0: x[N,128] @ W0[128,512]
  gemm_kernel<<<gL01, 256, 0, stream>>>(x, W0, A, N, 128, 512);
  stat_kernel<4><<<nwb, 256, 0, stream>>>(A, as0, ad0, asn, adn, N);
  agg_kernel<4, true><<<nwb, 256, 0, stream>>>(A, asn, adn, offs, srcs, b0, Bb, N);

  // layer 1: h0[N,512] @ W1[512,512]
  gemm_kernel<<<gL01, 256, 0, stream>>>(Bb, W1, A, N, 512, 512);
  stat_kernel<4><<<nwb, 256, 0, stream>>>(A, as1, ad1, asn, adn, N);
  agg_kernel<4, true><<<nwb, 256, 0, stream>>>(A, asn, adn, offs, srcs, b1, Bb, N);

  // layer 2: h1[N,512] @ W2[512,128], 1 head, no relu
  gemm_kernel<<<gL2, 256, 0, stream>>>(Bb, W2, A, N, 512, 128);
  stat_kernel<1><<<nwb, 256, 0, stream>>>(A, as2, ad2, asn, adn, N);
  float* h2 = A + (size_t)N * 128;     // disjoint from xl2 = A[0, N*128)
  agg_kernel<1, false><<<nwb, 256, 0, stream>>>(A, asn, adn, offs, srcs, b2, h2, N);

  // mean pool + MLP
  pool_kernel<<<128, 128, 0, stream>>>(h2, g, N);
  mlp_kernel<<<1, 64, 0, stream>>>(g, Wm1, bm1, Wm2, bm2, (float*)d_out, 1.0f / (float)N);
}

// Round 2
// 705.336 us; speedup vs baseline: 1.0085x; 1.0085x over previous
//
#include <hip/hip_runtime.h>
#include <math.h>

// ---------------------------------------------------------------------------
// GAT pipeline:
//   CSR build (count -> scan -> scatter)   [once per launch, inputs re-poisoned]
//   per layer: fp32 tiled GEMM -> per-node attention stats -> wave-per-node agg
//   mean pool -> 2-layer MLP -> scalar out
// R1: 128x128 / 8x8-per-thread GEMM for the N=512 layers (61 -> ~110 TF goal)
// ---------------------------------------------------------------------------

// ---------------- CSR build ----------------
__global__ void count_kernel(const int* __restrict__ ei, int* __restrict__ counts,
                             int E, int n) {
  int t = blockIdx.x * blockDim.x + threadIdx.x;
  if (t < E) {
    atomicAdd(&counts[ei[E + t]], 1);          // dst row of edge_index
  } else if (t < E + n) {
    atomicAdd(&counts[t - E], 1);              // self loop
  }
}

__global__ void scan_kernel(const int* __restrict__ counts, int* __restrict__ offsets,
                            int n) {
  __shared__ int sd[1024];
  __shared__ int carry_sh;
  int tid = threadIdx.x;
  if (tid == 0) carry_sh = 0;
  __syncthreads();
  for (int base = 0; base < n; base += 1024) {
    int i = base + tid;
    int v = (i < n) ? counts[i] : 0;
    sd[tid] = v;
    __syncthreads();
    for (int off = 1; off < 1024; off <<= 1) {
      int t = (tid >= off) ? sd[tid - off] : 0;
      __syncthreads();
      sd[tid] += t;
      __syncthreads();
    }
    int carry = carry_sh;
    if (i < n) offsets[i] = carry + sd[tid] - v;   // exclusive scan
    __syncthreads();
    if (tid == 1023) carry_sh = carry + sd[1023];
    __syncthreads();
  }
  if (tid == 0) offsets[n] = carry_sh;
}

__global__ void scatter_kernel(const int* __restrict__ ei, const int* __restrict__ offsets,
                               int* __restrict__ cursor, int* __restrict__ srcs,
                               int E, int n) {
  int t = blockIdx.x * blockDim.x + threadIdx.x;
  int s, d;
  if (t < E)          { s = ei[t]; d = ei[E + t]; }
  else if (t < E + n) { s = t - E; d = s; }
  else return;
  int pos = offsets[d] + atomicAdd(&cursor[d], 1);
  srcs[pos] = s;
}

// ---------------- fp32 GEMM, 128x128 block, 8x8/thread ----------------
// C[M,N] = A[M,K] @ B[K,N].  K%16==0, N%128==0. 256 threads.
__global__ __launch_bounds__(256, 2) void gemm128_kernel(
    const float* __restrict__ A, const float* __restrict__ B, float* __restrict__ C,
    int M, int K, int N) {
  __shared__ float As[16][132];   // [k][m], LD=132: transpose-write 2-way (free)
  __shared__ float Bs[16][128];   // [k][n]
  int tid = threadIdx.x;
  int tx = tid & 15, ty = tid >> 4;
  int row0 = blockIdx.y * 128, col0 = blockIdx.x * 128;
  int ar = tid >> 2, ak = (tid & 3) << 2;    // A: rows {ar, ar+64}, 4 k each
  int bk = tid >> 5, bn = (tid & 31) << 2;   // B: k rows {bk, bk+8}, 4 n each
  float acc[8][8] = {};
  for (int k0 = 0; k0 < K; k0 += 16) {
#pragma unroll
    for (int half = 0; half < 2; ++half) {
      int r = ar + half * 64;
      float4 av = make_float4(0.f, 0.f, 0.f, 0.f);
      if (row0 + r < M)
        av = *(const float4*)(A + (size_t)(row0 + r) * K + k0 + ak);
      As[ak + 0][r] = av.x; As[ak + 1][r] = av.y;
      As[ak + 2][r] = av.z; As[ak + 3][r] = av.w;
    }
#pragma unroll
    for (int half = 0; half < 2; ++half) {
      int kb = bk + half * 8;
      *(float4*)&Bs[kb][bn] = *(const float4*)(B + (size_t)(k0 + kb) * N + col0 + bn);
    }
    __syncthreads();
#pragma unroll
    for (int kk = 0; kk < 16; ++kk) {
      float a[8], b[8];
      *(float4*)&a[0] = *(const float4*)&As[kk][ty * 4];
      *(float4*)&a[4] = *(const float4*)&As[kk][64 + ty * 4];
      *(float4*)&b[0] = *(const float4*)&Bs[kk][tx * 4];
      *(float4*)&b[4] = *(const float4*)&Bs[kk][64 + tx * 4];
#pragma unroll
      for (int i = 0; i < 8; ++i)
#pragma unroll
        for (int j = 0; j < 8; ++j)
          acc[i][j] += a[i] * b[j];
    }
    __syncthreads();
  }
#pragma unroll
  for (int ih = 0; ih < 2; ++ih)
#pragma unroll
    for (int i = 0; i < 4; ++i) {
      int row = row0 + ih * 64 + ty * 4 + i;
      if (row < M) {
        int ia = ih * 4 + i;
        *(float4*)(C + (size_t)row * N + col0 + tx * 4) =
            make_float4(acc[ia][0], acc[ia][1], acc[ia][2], acc[ia][3]);
        *(float4*)(C + (size_t)row * N + col0 + 64 + tx * 4) =
            make_float4(acc[ia][4], acc[ia][5], acc[ia][6], acc[ia][7]);
      }
    }
}

// ---------------- fp32 tiled GEMM: 64x64, 4x4/thread (layer 2, N=128) -------
__global__ __launch_bounds__(256) void gemm_kernel(
    const float* __restrict__ A, const float* __restrict__ B, float* __restrict__ C,
    int M, int K, int N) {
  __shared__ float As[16][64 + 4];
  __shared__ float Bs[16][64];
  int tid = threadIdx.x;
  int tx = tid & 15, ty = tid >> 4;
  int row0 = blockIdx.y * 64, col0 = blockIdx.x * 64;
  int ar = tid >> 2, ak = (tid & 3) << 2;
  int bk = tid >> 4, bn = (tid & 15) << 2;
  float acc[4][4] = {};
  for (int k0 = 0; k0 < K; k0 += 16) {
    float4 av = make_float4(0.f, 0.f, 0.f, 0.f);
    if (row0 + ar < M)
      av = *(const float4*)(A + (size_t)(row0 + ar) * K + k0 + ak);
    As[ak + 0][ar] = av.x; As[ak + 1][ar] = av.y;
    As[ak + 2][ar] = av.z; As[ak + 3][ar] = av.w;
    float4 bv = *(const float4*)(B + (size_t)(k0 + bk) * N + col0 + bn);
    *(float4*)&Bs[bk][bn] = bv;
    __syncthreads();
#pragma unroll
    for (int kk = 0; kk < 16; ++kk) {
      float a0 = As[kk][ty * 4 + 0], a1 = As[kk][ty * 4 + 1];
      float a2 = As[kk][ty * 4 + 2], a3 = As[kk][ty * 4 + 3];
      float b0 = Bs[kk][tx * 4 + 0], b1 = Bs[kk][tx * 4 + 1];
      float b2 = Bs[kk][tx * 4 + 2], b3 = Bs[kk][tx * 4 + 3];
      acc[0][0] += a0 * b0; acc[0][1] += a0 * b1; acc[0][2] += a0 * b2; acc[0][3] += a0 * b3;
      acc[1][0] += a1 * b0; acc[1][1] += a1 * b1; acc[1][2] += a1 * b2; acc[1][3] += a1 * b3;
      acc[2][0] += a2 * b0; acc[2][1] += a2 * b1; acc[2][2] += a2 * b2; acc[2][3] += a2 * b3;
      acc[3][0] += a3 * b0; acc[3][1] += a3 * b1; acc[3][2] += a3 * b2; acc[3][3] += a3 * b3;
    }
    __syncthreads();
  }
#pragma unroll
  for (int i = 0; i < 4; ++i) {
    int row = row0 + ty * 4 + i;
    if (row < M) {
      float4 v = make_float4(acc[i][0], acc[i][1], acc[i][2], acc[i][3]);
      *(float4*)(C + (size_t)row * N + col0 + tx * 4) = v;
    }
  }
}

// ---------------- per-node attention stats: asn/adn[n,h] = <xl[n,h,:], a_{s,d}[h,:]>
template <int H>
__global__ __launch_bounds__(256) void stat_kernel(
    const float* __restrict__ xl, const float* __restrict__ a_s,
    const float* __restrict__ a_d, float* __restrict__ asn, float* __restrict__ adn,
    int n) {
  int wid = (blockIdx.x * blockDim.x + threadIdx.x) >> 6;
  int lane = threadIdx.x & 63;
  if (wid >= n) return;
  const float* row = xl + (size_t)wid * (H * 128);
#pragma unroll
  for (int h = 0; h < H; ++h) {
    float v0 = row[h * 128 + lane], v1 = row[h * 128 + 64 + lane];
    float ps = v0 * a_s[h * 128 + lane] + v1 * a_s[h * 128 + 64 + lane];
    float pd = v0 * a_d[h * 128 + lane] + v1 * a_d[h * 128 + 64 + lane];
    for (int m = 32; m; m >>= 1) {
      ps += __shfl_xor(ps, m);
      pd += __shfl_xor(pd, m);
    }
    if (lane == 0) { asn[wid * H + h] = ps; adn[wid * H + h] = pd; }
  }
}

// ---------------- wave-per-node softmax + aggregation ----------------
template <int H, bool RELU>
__global__ __launch_bounds__(256) void agg_kernel(
    const float* __restrict__ xl, const float* __restrict__ asn,
    const float* __restrict__ adn, const int* __restrict__ offsets,
    const int* __restrict__ srcs, const float* __restrict__ bias,
    float* __restrict__ out, int n) {
  constexpr int C = 128;
  constexpr int HC = H * C;
  constexpr int CPL = HC / 64;        // channels per lane: 8 (H=4) or 2 (H=1)
  __shared__ float alpha_sh[4][64 * H];
  __shared__ int src_sh[4][64];
  int wib = threadIdx.x >> 6;
  int lane = threadIdx.x & 63;
  int nd = blockIdx.x * 4 + wib;
  if (nd >= n) return;
  int beg = offsets[nd];
  int deg = offsets[nd + 1] - beg;
  float adl[H];
#pragma unroll
  for (int h = 0; h < H; ++h) adl[h] = adn[nd * H + h];

  // pass 1: per-head max of leaky_relu(asn[src]+adn[dst])
  float mh[H];
#pragma unroll
  for (int h = 0; h < H; ++h) mh[h] = -3.0e38f;
  for (int j0 = 0; j0 < deg; j0 += 64) {
    int j = j0 + lane;
    if (j < deg) {
      int s = srcs[beg + j];
#pragma unroll
      for (int h = 0; h < H; ++h) {
        float e = asn[s * H + h] + adl[h];
        e = (e > 0.f) ? e : 0.2f * e;
        mh[h] = fmaxf(mh[h], e);
      }
    }
  }
#pragma unroll
  for (int h = 0; h < H; ++h)
    for (int m = 32; m; m >>= 1) mh[h] = fmaxf(mh[h], __shfl_xor(mh[h], m));

  // pass 2: denominators
  float den[H];
#pragma unroll
  for (int h = 0; h < H; ++h) den[h] = 0.f;
  for (int j0 = 0; j0 < deg; j0 += 64) {
    int j = j0 + lane;
    if (j < deg) {
      int s = srcs[beg + j];
#pragma unroll
      for (int h = 0; h < H; ++h) {
        float e = asn[s * H + h] + adl[h];
        e = (e > 0.f) ? e : 0.2f * e;
        den[h] += expf(e - mh[h]);
      }
    }
  }
#pragma unroll
  for (int h = 0; h < H; ++h) {
    for (int m = 32; m; m >>= 1) den[h] += __shfl_xor(den[h], m);
    den[h] = 1.f / den[h];             // now holds 1/den
  }

  // pass 3: out[nd] = sum_j alpha_j * xl[src_j]
  float acc[CPL];
#pragma unroll
  for (int i = 0; i < CPL; ++i) acc[i] = 0.f;
  int ch0 = lane * CPL;
  int hm = ch0 / C;                    // my head
  for (int j0 = 0; j0 < deg; j0 += 64) {
    int j = j0 + lane;
    if (j < deg) {
      int s = srcs[beg + j];
      src_sh[wib][lane] = s;
#pragma unroll
      for (int h = 0; h < H; ++h) {
        float e = asn[s * H + h] + adl[h];
        e = (e > 0.f) ? e : 0.2f * e;
        alpha_sh[wib][lane * H + h] = expf(e - mh[h]) * den[h];
      }
    }
    __builtin_amdgcn_wave_barrier();   // wave-lockstep LDS producer->consumer
    int cl = min(64, deg - j0);
    for (int jj = 0; jj < cl; ++jj) {
      int s = src_sh[wib][jj];
      float a = alpha_sh[wib][jj * H + hm];
      const float* p = xl + (size_t)s * HC + ch0;
      if constexpr (CPL == 8) {
        float4 v0 = *(const float4*)p;
        float4 v1 = *(const float4*)(p + 4);
        acc[0] += a * v0.x; acc[1] += a * v0.y; acc[2] += a * v0.z; acc[3] += a * v0.w;
        acc[4] += a * v1.x; acc[5] += a * v1.y; acc[6] += a * v1.z; acc[7] += a * v1.w;
      } else {
        float2 v = *(const float2*)p;
        acc[0] += a * v.x; acc[1] += a * v.y;
      }
    }
    __builtin_amdgcn_wave_barrier();
  }
  float* op = out + (size_t)nd * HC + ch0;
#pragma unroll
  for (int i = 0; i < CPL; ++i) {
    float v = acc[i] + bias[ch0 + i];
    if (RELU) v = fmaxf(v, 0.f);
    op[i] = v;
  }
}

// ---------------- mean pool (partial sums + atomics) ----------------
__global__ void pool_kernel(const float* __restrict__ h, float* __restrict__ g, int n) {
  int c = threadIdx.x;                 // 128 threads
  float acc = 0.f;
  for (int r = blockIdx.x; r < n; r += gridDim.x) acc += h[(size_t)r * 128 + c];
  atomicAdd(&g[c], acc);
}

// ---------------- final MLP: relu(g/N @ Wm1 + bm1) @ Wm2 + bm2 ----------------
__global__ void mlp_kernel(const float* __restrict__ g, const float* __restrict__ Wm1,
                           const float* __restrict__ bm1, const float* __restrict__ Wm2,
                           const float* __restrict__ bm2, float* __restrict__ out,
                           float invn) {
  __shared__ float gs[128];
  __shared__ float hs[64];
  int t = threadIdx.x;                 // 64 threads
  gs[t] = g[t] * invn;
  gs[t + 64] = g[t + 64] * invn;
  __syncthreads();
  float acc = bm1[t];
  for (int c = 0; c < 128; ++c) acc += gs[c] * Wm1[c * 64 + t];
  hs[t] = fmaxf(acc, 0.f);
  __syncthreads();
  if (t == 0) {
    float o = bm2[0];
    for (int j = 0; j < 64; ++j) o += hs[j] * Wm2[j];
    out[0] = o;
  }
}

// ---------------------------------------------------------------------------
extern "C" void kernel_launch(void* const* d_in, const int* in_sizes, int n_in,
                              void* d_out, int out_size, void* d_ws, size_t ws_size,
                              hipStream_t stream) {
  const float* x   = (const float*)d_in[0];
  const int*   ei  = (const int*)d_in[1];
  const float* W0  = (const float*)d_in[2];
  const float* as0 = (const float*)d_in[3];
  const float* ad0 = (const float*)d_in[4];
  const float* b0  = (const float*)d_in[5];
  const float* W1  = (const float*)d_in[6];
  const float* as1 = (const float*)d_in[7];
  const float* ad1 = (const float*)d_in[8];
  const float* b1  = (const float*)d_in[9];
  const float* W2  = (const float*)d_in[10];
  const float* as2 = (const float*)d_in[11];
  const float* ad2 = (const float*)d_in[12];
  const float* b2  = (const float*)d_in[13];
  const float* Wm1 = (const float*)d_in[14];
  const float* bm1 = (const float*)d_in[15];
  const float* Wm2 = (const float*)d_in[16];
  const float* bm2 = (const float*)d_in[17];

  const int N = in_sizes[0] / 128;     // 20000
  const int E = in_sizes[1] / 2;       // 320000
  const int ET = E + N;                // with self loops

  // workspace layout (fp32 words)
  float* A    = (float*)d_ws;               // N*512  (xl of current layer; L2 out at +N*128)
  float* Bb   = A + (size_t)N * 512;        // N*512  (h between layers)
  float* asn  = Bb + (size_t)N * 512;       // N*4
  float* adn  = asn + (size_t)N * 4;        // N*4
  float* g    = adn + (size_t)N * 4;        // 128 pool accumulator
  int* counts = (int*)(g + 128);            // N
  int* cursor = counts + N;                 // N
  int* offs   = cursor + N;                 // N+1
  int* srcs   = offs + N + 1;               // ET

  // zero pool accumulator + counts + cursor (contiguous)
  hipMemsetAsync(g, 0, (size_t)(128 + 2 * N) * sizeof(int), stream);

  // CSR by dst
  int ebl = (ET + 255) / 256;
  count_kernel<<<ebl, 256, 0, stream>>>(ei, counts, E, N);
  scan_kernel<<<1, 1024, 0, stream>>>(counts, offs, N);
  scatter_kernel<<<ebl, 256, 0, stream>>>(ei, offs, cursor, srcs, E, N);

  int nwb = (N + 3) / 4;               // wave-per-node kernels: 4 waves/block
  dim3 gL01(512 / 128, (N + 127) / 128);   // 128x128 tiles for N=512 layers
  dim3 gL2(128 / 64, (N + 63) / 64);       // 64x64 tiles for layer 2

  // layer 0: x[N,128] @ W0[128,512]
  gemm128_kernel<<<gL01, 256, 0, stream>>>(x, W0, A, N, 128, 512);
  stat_kernel<4><<<nwb, 256, 0, stream>>>(A, as0, ad0, asn, adn, N);
  agg_kernel<4, true><<<nwb, 256, 0, stream>>>(A, asn, adn, offs, srcs, b0, Bb, N);

  // layer 1: h0[N,512] @ W1[512,512]
  gemm128_kernel<<<gL01, 256, 0, stream>>>(Bb, W1, A, N, 512, 512);
  stat_kernel<4><<<nwb, 256, 0, stream>>>(A, as1, ad1, asn, adn, N);
  agg_kernel<4, true><<<nwb, 256, 0, stream>>>(A, asn, adn, offs, srcs, b1, Bb, N);

  // layer 2: h1[N,512] @ W2[512,128], 1 head, no relu
  gemm_kernel<<<gL2, 256, 0, stream>>>(Bb, W2, A, N, 512, 128);
  stat_kernel<1><<<nwb, 256, 0, stream>>>(A, as2, ad2, asn, adn, N);
  float* h2 = A + (size_t)N * 128;     // disjoint from xl2 = A[0, N*128)
  agg_kernel<1, false><<<nwb, 256, 0, stream>>>(A, asn, adn, offs, srcs, b2, h2, N);

  // mean pool + MLP
  pool_kernel<<<128, 128, 0, stream>>>(h2, g, N);
  mlp_kernel<<<1, 64, 0, stream>>>(g, Wm1, bm1, Wm2, bm2, (float*)d_out, 1.0f / (float)N);
}

// Round 3
// 543.621 us; speedup vs baseline: 1.3085x; 1.2975x over previous
//
#include <hip/hip_runtime.h>
#include <math.h>

// ---------------------------------------------------------------------------
// GAT pipeline:
//   weight split+transpose (bf16 hi/lo) + CSR build   [once per launch]
//   per layer: split-bf16 MFMA GEMM -> per-node stats -> wave-per-node agg
//   mean pool -> 2-layer MLP -> scalar out
// R2 post-mortem: fp32 vector GEMM plateaus ~60TF (157TF VALU cap; 128-tile
//   hit occupancy cliff). R3: 3xbf16-split MFMA GEMM (ah*bh+ah*bl+al*bh),
//   ~2^-17 rel err, matrix pipe ~2.4PF ceiling.
// ---------------------------------------------------------------------------

typedef float f32x4 __attribute__((ext_vector_type(4)));
typedef short s16x8 __attribute__((ext_vector_type(8)));
typedef short s16x4 __attribute__((ext_vector_type(4)));

__device__ inline ushort f2bf(float f) {
  unsigned u = __float_as_uint(f);
  u += 0x7FFF + ((u >> 16) & 1);          // round-to-nearest-even
  return (ushort)(u >> 16);
}
__device__ inline float bf2f(ushort h) { return __uint_as_float((unsigned)h << 16); }

// ---------------- CSR build ----------------
__global__ void count_kernel(const int* __restrict__ ei, int* __restrict__ counts,
                             int E, int n) {
  int t = blockIdx.x * blockDim.x + threadIdx.x;
  if (t < E) {
    atomicAdd(&counts[ei[E + t]], 1);          // dst row of edge_index
  } else if (t < E + n) {
    atomicAdd(&counts[t - E], 1);              // self loop
  }
}

__global__ void scan_kernel(const int* __restrict__ counts, int* __restrict__ offsets,
                            int n) {
  __shared__ int sd[1024];
  __shared__ int carry_sh;
  int tid = threadIdx.x;
  if (tid == 0) carry_sh = 0;
  __syncthreads();
  for (int base = 0; base < n; base += 1024) {
    int i = base + tid;
    int v = (i < n) ? counts[i] : 0;
    sd[tid] = v;
    __syncthreads();
    for (int off = 1; off < 1024; off <<= 1) {
      int t = (tid >= off) ? sd[tid - off] : 0;
      __syncthreads();
      sd[tid] += t;
      __syncthreads();
    }
    int carry = carry_sh;
    if (i < n) offsets[i] = carry + sd[tid] - v;   // exclusive scan
    __syncthreads();
    if (tid == 1023) carry_sh = carry + sd[1023];
    __syncthreads();
  }
  if (tid == 0) offsets[n] = carry_sh;
}

__global__ void scatter_kernel(const int* __restrict__ ei, const int* __restrict__ offsets,
                               int* __restrict__ cursor, int* __restrict__ srcs,
                               int E, int n) {
  int t = blockIdx.x * blockDim.x + threadIdx.x;
  int s, d;
  if (t < E)          { s = ei[t]; d = ei[E + t]; }
  else if (t < E + n) { s = t - E; d = s; }
  else return;
  int pos = offsets[d] + atomicAdd(&cursor[d], 1);
  srcs[pos] = s;
}

// ---------------- weight transpose + bf16 split: W[K][N] -> th/tl[N][K] -----
__global__ void wsplit_kernel(const float* __restrict__ W, ushort* __restrict__ th,
                              ushort* __restrict__ tl, int K, int N) {
  int idx = blockIdx.x * 256 + threadIdx.x;
  if (idx >= (K >> 2) * N) return;
  int n = idx % N;
  int k4 = (idx / N) << 2;
  s16x4 hv, lv;
#pragma unroll
  for (int r = 0; r < 4; ++r) {
    float w = W[(size_t)(k4 + r) * N + n];
    ushort h = f2bf(w);
    hv[r] = (short)h;
    lv[r] = (short)f2bf(w - bf2f(h));
  }
  *(s16x4*)&th[(size_t)n * K + k4] = hv;
  *(s16x4*)&tl[(size_t)n * K + k4] = lv;
}

// ---------------- split-bf16 MFMA GEMM ----------------
// C[M,N] = A[M,K] @ B[K,N], A fp32 (split in-register), B pre-split [N][K].
// BM=64, BN=128, BK=32; 256 threads = 4 waves (2x2), wave = 32x64 = 2x4 MFMA
// tiles of 16x16x32. K%32==0, N%128==0. LDS rows padded to 40 ush (odd*16B).
__global__ __launch_bounds__(256, 2) void gemm_mfma_kernel(
    const float* __restrict__ A, const ushort* __restrict__ Bth,
    const ushort* __restrict__ Btl, float* __restrict__ C, int M, int K, int N) {
  __shared__ ushort Ash[64][40], Asl[64][40];
  __shared__ ushort Bsh[128][40], Bsl[128][40];
  int tid = threadIdx.x;
  int row0 = blockIdx.y * 64, col0 = blockIdx.x * 128;
  int am = tid >> 2, ak = (tid & 3) << 3;     // A stage: row am, 8 k-vals
  int bn = tid >> 1, bk = (tid & 1) << 4;     // B stage: row bn, 16 k-vals
  int lane = tid & 63, wid = tid >> 6;
  int wm = (wid & 1) << 5, wn = (wid >> 1) << 6;
  int fr = lane & 15, fq = (lane >> 4) << 3;  // fragment row/col, k-offset
  f32x4 acc[2][4] = {};
  const float* Arow = A + (size_t)(row0 + am) * K;
  bool avalid = (row0 + am) < M;
  const ushort* bhp = Bth + (size_t)(col0 + bn) * K + bk;
  const ushort* blp = Btl + (size_t)(col0 + bn) * K + bk;

  for (int k0 = 0; k0 < K; k0 += 32) {
    // ---- stage A (fp32 -> hi/lo bf16) ----
    float v[8];
    if (avalid) {
      float4 t0 = *(const float4*)(Arow + k0 + ak);
      float4 t1 = *(const float4*)(Arow + k0 + ak + 4);
      v[0] = t0.x; v[1] = t0.y; v[2] = t0.z; v[3] = t0.w;
      v[4] = t1.x; v[5] = t1.y; v[6] = t1.z; v[7] = t1.w;
    } else {
#pragma unroll
      for (int r = 0; r < 8; ++r) v[r] = 0.f;
    }
    s16x8 hv, lv;
#pragma unroll
    for (int r = 0; r < 8; ++r) {
      ushort h = f2bf(v[r]);
      hv[r] = (short)h;
      lv[r] = (short)f2bf(v[r] - bf2f(h));
    }
    *(s16x8*)&Ash[am][ak] = hv;
    *(s16x8*)&Asl[am][ak] = lv;
    // ---- stage B (pre-split ushort copy) ----
    *(s16x8*)&Bsh[bn][bk]     = *(const s16x8*)(bhp + k0);
    *(s16x8*)&Bsh[bn][bk + 8] = *(const s16x8*)(bhp + k0 + 8);
    *(s16x8*)&Bsl[bn][bk]     = *(const s16x8*)(blp + k0);
    *(s16x8*)&Bsl[bn][bk + 8] = *(const s16x8*)(blp + k0 + 8);
    __syncthreads();
    // ---- fragments + MFMA ----
    s16x8 ah[2], al[2], bh[4], bl[4];
#pragma unroll
    for (int i = 0; i < 2; ++i) {
      ah[i] = *(const s16x8*)&Ash[wm + i * 16 + fr][fq];
      al[i] = *(const s16x8*)&Asl[wm + i * 16 + fr][fq];
    }
#pragma unroll
    for (int j = 0; j < 4; ++j) {
      bh[j] = *(const s16x8*)&Bsh[wn + j * 16 + fr][fq];
      bl[j] = *(const s16x8*)&Bsl[wn + j * 16 + fr][fq];
    }
#pragma unroll
    for (int i = 0; i < 2; ++i)
#pragma unroll
      for (int j = 0; j < 4; ++j) {
        acc[i][j] = __builtin_amdgcn_mfma_f32_16x16x32_bf16(ah[i], bh[j], acc[i][j], 0, 0, 0);
        acc[i][j] = __builtin_amdgcn_mfma_f32_16x16x32_bf16(ah[i], bl[j], acc[i][j], 0, 0, 0);
        acc[i][j] = __builtin_amdgcn_mfma_f32_16x16x32_bf16(al[i], bh[j], acc[i][j], 0, 0, 0);
      }
    __syncthreads();
  }
  // ---- epilogue: C/D layout col=lane&15, row=(lane>>4)*4+reg ----
  int rb = row0 + wm + ((lane >> 4) << 2);
  int cb = col0 + wn + fr;
#pragma unroll
  for (int i = 0; i < 2; ++i)
#pragma unroll
    for (int r = 0; r < 4; ++r) {
      int row = rb + i * 16 + r;
      if (row < M) {
#pragma unroll
        for (int j = 0; j < 4; ++j)
          C[(size_t)row * N + cb + j * 16] = acc[i][j][r];
      }
    }
}

// ---------------- per-node attention stats: asn/adn[n,h] = <xl[n,h,:], a_{s,d}[h,:]>
template <int H>
__global__ __launch_bounds__(256) void stat_kernel(
    const float* __restrict__ xl, const float* __restrict__ a_s,
    const float* __restrict__ a_d, float* __restrict__ asn, float* __restrict__ adn,
    int n) {
  int wid = (blockIdx.x * blockDim.x + threadIdx.x) >> 6;
  int lane = threadIdx.x & 63;
  if (wid >= n) return;
  const float* row = xl + (size_t)wid * (H * 128);
#pragma unroll
  for (int h = 0; h < H; ++h) {
    float v0 = row[h * 128 + lane], v1 = row[h * 128 + 64 + lane];
    float ps = v0 * a_s[h * 128 + lane] + v1 * a_s[h * 128 + 64 + lane];
    float pd = v0 * a_d[h * 128 + lane] + v1 * a_d[h * 128 + 64 + lane];
    for (int m = 32; m; m >>= 1) {
      ps += __shfl_xor(ps, m);
      pd += __shfl_xor(pd, m);
    }
    if (lane == 0) { asn[wid * H + h] = ps; adn[wid * H + h] = pd; }
  }
}

// ---------------- wave-per-node softmax + aggregation ----------------
template <int H, bool RELU>
__global__ __launch_bounds__(256) void agg_kernel(
    const float* __restrict__ xl, const float* __restrict__ asn,
    const float* __restrict__ adn, const int* __restrict__ offsets,
    const int* __restrict__ srcs, const float* __restrict__ bias,
    float* __restrict__ out, int n) {
  constexpr int C = 128;
  constexpr int HC = H * C;
  constexpr int CPL = HC / 64;        // channels per lane: 8 (H=4) or 2 (H=1)
  __shared__ float alpha_sh[4][64 * H];
  __shared__ int src_sh[4][64];
  int wib = threadIdx.x >> 6;
  int lane = threadIdx.x & 63;
  int nd = blockIdx.x * 4 + wib;
  if (nd >= n) return;
  int beg = offsets[nd];
  int deg = offsets[nd + 1] - beg;
  float adl[H];
#pragma unroll
  for (int h = 0; h < H; ++h) adl[h] = adn[nd * H + h];

  // pass 1: per-head max of leaky_relu(asn[src]+adn[dst])
  float mh[H];
#pragma unroll
  for (int h = 0; h < H; ++h) mh[h] = -3.0e38f;
  for (int j0 = 0; j0 < deg; j0 += 64) {
    int j = j0 + lane;
    if (j < deg) {
      int s = srcs[beg + j];
#pragma unroll
      for (int h = 0; h < H; ++h) {
        float e = asn[s * H + h] + adl[h];
        e = (e > 0.f) ? e : 0.2f * e;
        mh[h] = fmaxf(mh[h], e);
      }
    }
  }
#pragma unroll
  for (int h = 0; h < H; ++h)
    for (int m = 32; m; m >>= 1) mh[h] = fmaxf(mh[h], __shfl_xor(mh[h], m));

  // pass 2: denominators
  float den[H];
#pragma unroll
  for (int h = 0; h < H; ++h) den[h] = 0.f;
  for (int j0 = 0; j0 < deg; j0 += 64) {
    int j = j0 + lane;
    if (j < deg) {
      int s = srcs[beg + j];
#pragma unroll
      for (int h = 0; h < H; ++h) {
        float e = asn[s * H + h] + adl[h];
        e = (e > 0.f) ? e : 0.2f * e;
        den[h] += expf(e - mh[h]);
      }
    }
  }
#pragma unroll
  for (int h = 0; h < H; ++h) {
    for (int m = 32; m; m >>= 1) den[h] += __shfl_xor(den[h], m);
    den[h] = 1.f / den[h];             // now holds 1/den
  }

  // pass 3: out[nd] = sum_j alpha_j * xl[src_j]
  float acc[CPL];
#pragma unroll
  for (int i = 0; i < CPL; ++i) acc[i] = 0.f;
  int ch0 = lane * CPL;
  int hm = ch0 / C;                    // my head
  for (int j0 = 0; j0 < deg; j0 += 64) {
    int j = j0 + lane;
    if (j < deg) {
      int s = srcs[beg + j];
      src_sh[wib][lane] = s;
#pragma unroll
      for (int h = 0; h < H; ++h) {
        float e = asn[s * H + h] + adl[h];
        e = (e > 0.f) ? e : 0.2f * e;
        alpha_sh[wib][lane * H + h] = expf(e - mh[h]) * den[h];
      }
    }
    __builtin_amdgcn_wave_barrier();   // wave-lockstep LDS producer->consumer
    int cl = min(64, deg - j0);
    for (int jj = 0; jj < cl; ++jj) {
      int s = src_sh[wib][jj];
      float a = alpha_sh[wib][jj * H + hm];
      const float* p = xl + (size_t)s * HC + ch0;
      if constexpr (CPL == 8) {
        float4 v0 = *(const float4*)p;
        float4 v1 = *(const float4*)(p + 4);
        acc[0] += a * v0.x; acc[1] += a * v0.y; acc[2] += a * v0.z; acc[3] += a * v0.w;
        acc[4] += a * v1.x; acc[5] += a * v1.y; acc[6] += a * v1.z; acc[7] += a * v1.w;
      } else {
        float2 v = *(const float2*)p;
        acc[0] += a * v.x; acc[1] += a * v.y;
      }
    }
    __builtin_amdgcn_wave_barrier();
  }
  float* op = out + (size_t)nd * HC + ch0;
#pragma unroll
  for (int i = 0; i < CPL; ++i) {
    float v = acc[i] + bias[ch0 + i];
    if (RELU) v = fmaxf(v, 0.f);
    op[i] = v;
  }
}

// ---------------- mean pool (partial sums + atomics) ----------------
__global__ void pool_kernel(const float* __restrict__ h, float* __restrict__ g, int n) {
  int c = threadIdx.x;                 // 128 threads
  float acc = 0.f;
  for (int r = blockIdx.x; r < n; r += gridDim.x) acc += h[(size_t)r * 128 + c];
  atomicAdd(&g[c], acc);
}

// ---------------- final MLP: relu(g/N @ Wm1 + bm1) @ Wm2 + bm2 ----------------
__global__ void mlp_kernel(const float* __restrict__ g, const float* __restrict__ Wm1,
                           const float* __restrict__ bm1, const float* __restrict__ Wm2,
                           const float* __restrict__ bm2, float* __restrict__ out,
                           float invn) {
  __shared__ float gs[128];
  __shared__ float hs[64];
  int t = threadIdx.x;                 // 64 threads
  gs[t] = g[t] * invn;
  gs[t + 64] = g[t + 64] * invn;
  __syncthreads();
  float acc = bm1[t];
  for (int c = 0; c < 128; ++c) acc += gs[c] * Wm1[c * 64 + t];
  hs[t] = fmaxf(acc, 0.f);
  __syncthreads();
  if (t == 0) {
    float o = bm2[0];
    for (int j = 0; j < 64; ++j) o += hs[j] * Wm2[j];
    out[0] = o;
  }
}

// ---------------------------------------------------------------------------
extern "C" void kernel_launch(void* const* d_in, const int* in_sizes, int n_in,
                              void* d_out, int out_size, void* d_ws, size_t ws_size,
                              hipStream_t stream) {
  const float* x   = (const float*)d_in[0];
  const int*   ei  = (const int*)d_in[1];
  const float* W0  = (const float*)d_in[2];
  const float* as0 = (const float*)d_in[3];
  const float* ad0 = (const float*)d_in[4];
  const float* b0  = (const float*)d_in[5];
  const float* W1  = (const float*)d_in[6];
  const float* as1 = (const float*)d_in[7];
  const float* ad1 = (const float*)d_in[8];
  const float* b1  = (const float*)d_in[9];
  const float* W2  = (const float*)d_in[10];
  const float* as2 = (const float*)d_in[11];
  const float* ad2 = (const float*)d_in[12];
  const float* b2  = (const float*)d_in[13];
  const float* Wm1 = (const float*)d_in[14];
  const float* bm1 = (const float*)d_in[15];
  const float* Wm2 = (const float*)d_in[16];
  const float* bm2 = (const float*)d_in[17];

  const int N = in_sizes[0] / 128;     // 20000
  const int E = in_sizes[1] / 2;       // 320000
  const int ET = E + N;                // with self loops

  // workspace layout (fp32 words)
  float* A    = (float*)d_ws;               // N*512  (xl of current layer; L2 out at +N*128)
  float* Bb   = A + (size_t)N * 512;        // N*512  (h between layers)
  float* asn  = Bb + (size_t)N * 512;       // N*4
  float* adn  = asn + (size_t)N * 4;        // N*4
  float* g    = adn + (size_t)N * 4;        // 128 pool accumulator
  int* counts = (int*)(g + 128);            // N
  int* cursor = counts + N;                 // N
  int* offs   = cursor + N;                 // N+1
  int* srcs   = offs + N + 1;               // ET
  // transposed+split weights (ushort), 64B-aligned
  ushort* w0h = (ushort*)(((uintptr_t)(srcs + ET) + 63) & ~(uintptr_t)63);
  ushort* w0l = w0h + 512 * 128;
  ushort* w1h = w0l + 512 * 128;
  ushort* w1l = w1h + 512 * 512;
  ushort* w2h = w1l + 512 * 512;
  ushort* w2l = w2h + 128 * 512;

  // zero pool accumulator + counts + cursor (contiguous)
  hipMemsetAsync(g, 0, (size_t)(128 + 2 * N) * sizeof(int), stream);

  // weight transpose + split (tiny)
  wsplit_kernel<<<(128 / 4 * 512 + 255) / 256, 256, 0, stream>>>(W0, w0h, w0l, 128, 512);
  wsplit_kernel<<<(512 / 4 * 512 + 255) / 256, 256, 0, stream>>>(W1, w1h, w1l, 512, 512);
  wsplit_kernel<<<(512 / 4 * 128 + 255) / 256, 256, 0, stream>>>(W2, w2h, w2l, 512, 128);

  // CSR by dst
  int ebl = (ET + 255) / 256;
  count_kernel<<<ebl, 256, 0, stream>>>(ei, counts, E, N);
  scan_kernel<<<1, 1024, 0, stream>>>(counts, offs, N);
  scatter_kernel<<<ebl, 256, 0, stream>>>(ei, offs, cursor, srcs, E, N);

  int nwb = (N + 3) / 4;               // wave-per-node kernels: 4 waves/block
  dim3 gG01(512 / 128, (N + 63) / 64); // (4, 313)
  dim3 gG2(128 / 128, (N + 63) / 64);  // (1, 313)

  // layer 0: x[N,128] @ W0[128,512]
  gemm_mfma_kernel<<<gG01, 256, 0, stream>>>(x, w0h, w0l, A, N, 128, 512);
  stat_kernel<4><<<nwb, 256, 0, stream>>>(A, as0, ad0, asn, adn, N);
  agg_kernel<4, true><<<nwb, 256, 0, stream>>>(A, asn, adn, offs, srcs, b0, Bb, N);

  // layer 1: h0[N,512] @ W1[512,512]
  gemm_mfma_kernel<<<gG01, 256, 0, stream>>>(Bb, w1h, w1l, A, N, 512, 512);
  stat_kernel<4><<<nwb, 256, 0, stream>>>(A, as1, ad1, asn, adn, N);
  agg_kernel<4, true><<<nwb, 256, 0, stream>>>(A, asn, adn, offs, srcs, b1, Bb, N);

  // layer 2: h1[N,512] @ W2[512,128], 1 head, no relu
  gemm_mfma_kernel<<<gG2, 256, 0, stream>>>(Bb, w2h, w2l, A, N, 512, 128);
  stat_kernel<1><<<nwb, 256, 0, stream>>>(A, as2, ad2, asn, adn, N);
  float* h2 = A + (size_t)N * 128;     // disjoint from xl2 = A[0, N*128)
  agg_kernel<1, false><<<nwb, 256, 0, stream>>>(A, asn, adn, offs, srcs, b2, h2, N);

  // mean pool + MLP
  pool_kernel<<<128, 128, 0, stream>>>(h2, g, N);
  mlp_kernel<<<1, 64, 0, stream>>>(g, Wm1, bm1, Wm2, bm2, (float*)d_out, 1.0f / (float)N);
}

// Round 4
// 421.634 us; speedup vs baseline: 1.6870x; 1.2893x over previous
//
#include <hip/hip_runtime.h>
#include <math.h>

// ---------------------------------------------------------------------------
// GAT pipeline (R4):
//   wsplit (one kernel) + CSR build  [once per launch]
//   per layer: split-bf16 MFMA GEMM (fused per-head attn stats, bf16 xl out)
//              -> wave-per-node online-softmax agg (bf16 gather, fp32 acc)
//   mean pool -> 2-layer MLP -> scalar out
// R3 post-mortem: agg gather is BW-bound (319MB fetch, 3.7TB/s, 98us).
// R4: halve gather payload (bf16 xl), fuse stats into GEMM epilogue (exact,
//     pre-rounding), single-pass online softmax.
// ---------------------------------------------------------------------------

typedef float f32x4 __attribute__((ext_vector_type(4)));
typedef short s16x8 __attribute__((ext_vector_type(8)));
typedef short s16x4 __attribute__((ext_vector_type(4)));

__device__ inline ushort f2bf(float f) {
  unsigned u = __float_as_uint(f);
  u += 0x7FFF + ((u >> 16) & 1);          // round-to-nearest-even
  return (ushort)(u >> 16);
}
__device__ inline float bf2f(ushort h) { return __uint_as_float((unsigned)h << 16); }

// ---------------- CSR build ----------------
__global__ void count_kernel(const int* __restrict__ ei, int* __restrict__ counts,
                             int E, int n) {
  int t = blockIdx.x * blockDim.x + threadIdx.x;
  if (t < E) {
    atomicAdd(&counts[ei[E + t]], 1);          // dst row of edge_index
  } else if (t < E + n) {
    atomicAdd(&counts[t - E], 1);              // self loop
  }
}

__global__ void scan_kernel(const int* __restrict__ counts, int* __restrict__ offsets,
                            int n) {
  __shared__ int sd[1024];
  __shared__ int carry_sh;
  int tid = threadIdx.x;
  if (tid == 0) carry_sh = 0;
  __syncthreads();
  for (int base = 0; base < n; base += 1024) {
    int i = base + tid;
    int v = (i < n) ? counts[i] : 0;
    sd[tid] = v;
    __syncthreads();
    for (int off = 1; off < 1024; off <<= 1) {
      int t = (tid >= off) ? sd[tid - off] : 0;
      __syncthreads();
      sd[tid] += t;
      __syncthreads();
    }
    int carry = carry_sh;
    if (i < n) offsets[i] = carry + sd[tid] - v;   // exclusive scan
    __syncthreads();
    if (tid == 1023) carry_sh = carry + sd[1023];
    __syncthreads();
  }
  if (tid == 0) offsets[n] = carry_sh;
}

__global__ void scatter_kernel(const int* __restrict__ ei, const int* __restrict__ offsets,
                               int* __restrict__ cursor, int* __restrict__ srcs,
                               int E, int n) {
  int t = blockIdx.x * blockDim.x + threadIdx.x;
  int s, d;
  if (t < E)          { s = ei[t]; d = ei[E + t]; }
  else if (t < E + n) { s = t - E; d = s; }
  else return;
  int pos = offsets[d] + atomicAdd(&cursor[d], 1);
  srcs[pos] = s;
}

// ------- weight transpose + bf16 split for all 3 layers in one launch -------
__global__ void wsplit_all_kernel(
    const float* __restrict__ W0, const float* __restrict__ W1,
    const float* __restrict__ W2, ushort* __restrict__ w0h, ushort* __restrict__ w0l,
    ushort* __restrict__ w1h, ushort* __restrict__ w1l, ushort* __restrict__ w2h,
    ushort* __restrict__ w2l) {
  int idx = blockIdx.x * 256 + threadIdx.x;
  const float* W; ushort *th, *tl; int K, N;
  if (idx < 16384)      { W = W0; th = w0h; tl = w0l; K = 128; N = 512; }
  else if (idx < 81920) { idx -= 16384; W = W1; th = w1h; tl = w1l; K = 512; N = 512; }
  else if (idx < 98304) { idx -= 81920; W = W2; th = w2h; tl = w2l; K = 512; N = 128; }
  else return;
  int n = idx % N;
  int k4 = (idx / N) << 2;
  s16x4 hv, lv;
#pragma unroll
  for (int r = 0; r < 4; ++r) {
    float w = W[(size_t)(k4 + r) * N + n];
    ushort h = f2bf(w);
    hv[r] = (short)h;
    lv[r] = (short)f2bf(w - bf2f(h));
  }
  *(s16x4*)&th[(size_t)n * K + k4] = hv;
  *(s16x4*)&tl[(size_t)n * K + k4] = lv;
}

// ---------------- split-bf16 MFMA GEMM + fused per-head attn stats ----------
// Cb[M,N] (bf16) = A[M,K] @ B[K,N]; block col range = one head (128 cols).
// asn/adn[M,H] = per-row dot of fp32 accum with a_s/a_d[h,0:128] (exact).
// BM=64, BN=128, BK=32; 256 threads = 4 waves (2x2), 16x16x32 MFMA.
__global__ __launch_bounds__(256, 2) void gemm_mfma_kernel(
    const float* __restrict__ A, const ushort* __restrict__ Bth,
    const ushort* __restrict__ Btl, ushort* __restrict__ Cb,
    const float* __restrict__ a_s, const float* __restrict__ a_d,
    float* __restrict__ asn, float* __restrict__ adn,
    int M, int K, int N, int H) {
  __shared__ ushort Ash[64][40], Asl[64][40];
  __shared__ ushort Bsh[128][40], Bsl[128][40];
  __shared__ float st_sh[2][64][2];           // [src/dst][row][wave-col-half]
  int tid = threadIdx.x;
  int row0 = blockIdx.y * 64, col0 = blockIdx.x * 128;
  int hidx = blockIdx.x;                      // head index (N==H*128)
  int am = tid >> 2, ak = (tid & 3) << 3;     // A stage: row am, 8 k-vals
  int bn = tid >> 1, bk = (tid & 1) << 4;     // B stage: row bn, 16 k-vals
  int lane = tid & 63, wid = tid >> 6;
  int wm = (wid & 1) << 5, wn = (wid >> 1) << 6;
  int fr = lane & 15, fq = (lane >> 4) << 3;  // fragment row/col, k-offset
  f32x4 acc[2][4] = {};
  const float* Arow = A + (size_t)(row0 + am) * K;
  bool avalid = (row0 + am) < M;
  const ushort* bhp = Bth + (size_t)(col0 + bn) * K + bk;
  const ushort* blp = Btl + (size_t)(col0 + bn) * K + bk;

  for (int k0 = 0; k0 < K; k0 += 32) {
    // ---- stage A (fp32 -> hi/lo bf16) ----
    float v[8];
    if (avalid) {
      float4 t0 = *(const float4*)(Arow + k0 + ak);
      float4 t1 = *(const float4*)(Arow + k0 + ak + 4);
      v[0] = t0.x; v[1] = t0.y; v[2] = t0.z; v[3] = t0.w;
      v[4] = t1.x; v[5] = t1.y; v[6] = t1.z; v[7] = t1.w;
    } else {
#pragma unroll
      for (int r = 0; r < 8; ++r) v[r] = 0.f;
    }
    s16x8 hv, lv;
#pragma unroll
    for (int r = 0; r < 8; ++r) {
      ushort h = f2bf(v[r]);
      hv[r] = (short)h;
      lv[r] = (short)f2bf(v[r] - bf2f(h));
    }
    *(s16x8*)&Ash[am][ak] = hv;
    *(s16x8*)&Asl[am][ak] = lv;
    // ---- stage B (pre-split ushort copy) ----
    *(s16x8*)&Bsh[bn][bk]     = *(const s16x8*)(bhp + k0);
    *(s16x8*)&Bsh[bn][bk + 8] = *(const s16x8*)(bhp + k0 + 8);
    *(s16x8*)&Bsl[bn][bk]     = *(const s16x8*)(blp + k0);
    *(s16x8*)&Bsl[bn][bk + 8] = *(const s16x8*)(blp + k0 + 8);
    __syncthreads();
    // ---- fragments + MFMA (ah*bh + ah*bl + al*bh) ----
    s16x8 ah[2], al[2], bh[4], bl[4];
#pragma unroll
    for (int i = 0; i < 2; ++i) {
      ah[i] = *(const s16x8*)&Ash[wm + i * 16 + fr][fq];
      al[i] = *(const s16x8*)&Asl[wm + i * 16 + fr][fq];
    }
#pragma unroll
    for (int j = 0; j < 4; ++j) {
      bh[j] = *(const s16x8*)&Bsh[wn + j * 16 + fr][fq];
      bl[j] = *(const s16x8*)&Bsl[wn + j * 16 + fr][fq];
    }
#pragma unroll
    for (int i = 0; i < 2; ++i)
#pragma unroll
      for (int j = 0; j < 4; ++j) {
        acc[i][j] = __builtin_amdgcn_mfma_f32_16x16x32_bf16(ah[i], bh[j], acc[i][j], 0, 0, 0);
        acc[i][j] = __builtin_amdgcn_mfma_f32_16x16x32_bf16(ah[i], bl[j], acc[i][j], 0, 0, 0);
        acc[i][j] = __builtin_amdgcn_mfma_f32_16x16x32_bf16(al[i], bh[j], acc[i][j], 0, 0, 0);
      }
    __syncthreads();
  }
  // ---- epilogue: bf16 store + fused stats ----
  // C/D layout: col = lane&15 (fr), row = (lane>>4)*4 + reg
  float asv[4], adv[4];
#pragma unroll
  for (int j = 0; j < 4; ++j) {
    asv[j] = a_s[hidx * 128 + wn + j * 16 + fr];
    adv[j] = a_d[hidx * 128 + wn + j * 16 + fr];
  }
  int rb = row0 + wm + ((lane >> 4) << 2);
  int cb = col0 + wn + fr;
#pragma unroll
  for (int i = 0; i < 2; ++i)
#pragma unroll
    for (int r = 0; r < 4; ++r) {
      int row = rb + i * 16 + r;
      float sp = 0.f, dp = 0.f;
#pragma unroll
      for (int j = 0; j < 4; ++j) {
        float c = acc[i][j][r];
        sp += c * asv[j];
        dp += c * adv[j];
        if (row < M) Cb[(size_t)row * N + cb + j * 16] = f2bf(c);
      }
      // reduce over fr (16 lanes per row-group)
#pragma unroll
      for (int m = 1; m < 16; m <<= 1) {
        sp += __shfl_xor(sp, m);
        dp += __shfl_xor(dp, m);
      }
      if ((lane & 15) == 0) {
        int rowb = wm + i * 16 + ((lane >> 4) << 2) + r;
        st_sh[0][rowb][wid >> 1] = sp;
        st_sh[1][rowb][wid >> 1] = dp;
      }
    }
  __syncthreads();
  if (tid < 64) {
    int row = row0 + tid;
    if (row < M) {
      asn[(size_t)row * H + hidx] = st_sh[0][tid][0] + st_sh[0][tid][1];
      adn[(size_t)row * H + hidx] = st_sh[1][tid][0] + st_sh[1][tid][1];
    }
  }
}

// ------- wave-per-node online-softmax + bf16 gather aggregation -------
template <int H, bool RELU>
__global__ __launch_bounds__(256) void agg_kernel(
    const ushort* __restrict__ xl, const float* __restrict__ asn,
    const float* __restrict__ adn, const int* __restrict__ offsets,
    const int* __restrict__ srcs, const float* __restrict__ bias,
    float* __restrict__ out, int n) {
  constexpr int C = 128;
  constexpr int HC = H * C;
  constexpr int CPL = HC / 64;        // channels per lane: 8 (H=4) or 2 (H=1)
  __shared__ float alpha_sh[4][64 * H];
  __shared__ int src_sh[4][64];
  int wib = threadIdx.x >> 6;
  int lane = threadIdx.x & 63;
  int nd = blockIdx.x * 4 + wib;
  if (nd >= n) return;
  int beg = offsets[nd];
  int deg = offsets[nd + 1] - beg;
  float adl[H];
#pragma unroll
  for (int h = 0; h < H; ++h) adl[h] = adn[nd * H + h];

  // single pass: per-lane online (m, l) per head
  float mh[H], lh[H];
#pragma unroll
  for (int h = 0; h < H; ++h) { mh[h] = -3.0e38f; lh[h] = 0.f; }
  for (int j0 = 0; j0 < deg; j0 += 64) {
    int j = j0 + lane;
    if (j < deg) {
      int s = srcs[beg + j];
      float ev[H];
      if constexpr (H == 4) {
        float4 av = *(const float4*)&asn[(size_t)s * 4];
        ev[0] = av.x; ev[1] = av.y; ev[2] = av.z; ev[3] = av.w;
      } else {
        ev[0] = asn[s];
      }
#pragma unroll
      for (int h = 0; h < H; ++h) {
        float e = ev[h] + adl[h];
        e = (e > 0.f) ? e : 0.2f * e;
        float mn = fmaxf(mh[h], e);
        lh[h] = lh[h] * __expf(mh[h] - mn) + __expf(e - mn);
        mh[h] = mn;
      }
    }
  }
  // butterfly merge of (m,l)
#pragma unroll
  for (int h = 0; h < H; ++h) {
    for (int m = 1; m < 64; m <<= 1) {
      float mo = __shfl_xor(mh[h], m);
      float lo = __shfl_xor(lh[h], m);
      float mn = fmaxf(mh[h], mo);
      lh[h] = lh[h] * __expf(mh[h] - mn) + lo * __expf(mo - mn);
      mh[h] = mn;
    }
    lh[h] = 1.f / lh[h];               // 1/den
  }

  // gather pass: out[nd] = sum_j alpha_j * xl[src_j]  (bf16 payload)
  float acc[CPL];
#pragma unroll
  for (int i = 0; i < CPL; ++i) acc[i] = 0.f;
  int ch0 = lane * CPL;
  int hm = ch0 / C;                    // my head
  for (int j0 = 0; j0 < deg; j0 += 64) {
    int j = j0 + lane;
    if (j < deg) {
      int s = srcs[beg + j];
      src_sh[wib][lane] = s;
      float ev[H];
      if constexpr (H == 4) {
        float4 av = *(const float4*)&asn[(size_t)s * 4];
        ev[0] = av.x; ev[1] = av.y; ev[2] = av.z; ev[3] = av.w;
      } else {
        ev[0] = asn[s];
      }
#pragma unroll
      for (int h = 0; h < H; ++h) {
        float e = ev[h] + adl[h];
        e = (e > 0.f) ? e : 0.2f * e;
        alpha_sh[wib][lane * H + h] = __expf(e - mh[h]) * lh[h];
      }
    }
    __builtin_amdgcn_wave_barrier();   // wave-lockstep LDS producer->consumer
    int cl = min(64, deg - j0);
    for (int jj = 0; jj < cl; ++jj) {
      int s = src_sh[wib][jj];
      float a = alpha_sh[wib][jj * H + hm];
      const ushort* p = xl + (size_t)s * HC + ch0;
      if constexpr (CPL == 8) {
        s16x8 v = *(const s16x8*)p;
#pragma unroll
        for (int i = 0; i < 8; ++i) acc[i] += a * bf2f((ushort)v[i]);
      } else {
        uint v = *(const uint*)p;
        acc[0] += a * bf2f((ushort)(v & 0xFFFF));
        acc[1] += a * bf2f((ushort)(v >> 16));
      }
    }
    __builtin_amdgcn_wave_barrier();
  }
  float* op = out + (size_t)nd * HC + ch0;
#pragma unroll
  for (int i = 0; i < CPL; ++i) {
    float v = acc[i] + bias[ch0 + i];
    if (RELU) v = fmaxf(v, 0.f);
    op[i] = v;
  }
}

// ---------------- mean pool (partial sums + atomics) ----------------
__global__ void pool_kernel(const float* __restrict__ h, float* __restrict__ g, int n) {
  int c = threadIdx.x;                 // 128 threads
  float acc = 0.f;
  for (int r = blockIdx.x; r < n; r += gridDim.x) acc += h[(size_t)r * 128 + c];
  atomicAdd(&g[c], acc);
}

// ---------------- final MLP: relu(g/N @ Wm1 + bm1) @ Wm2 + bm2 ----------------
__global__ void mlp_kernel(const float* __restrict__ g, const float* __restrict__ Wm1,
                           const float* __restrict__ bm1, const float* __restrict__ Wm2,
                           const float* __restrict__ bm2, float* __restrict__ out,
                           float invn) {
  __shared__ float gs[128];
  __shared__ float hs[64];
  int t = threadIdx.x;                 // 64 threads
  gs[t] = g[t] * invn;
  gs[t + 64] = g[t + 64] * invn;
  __syncthreads();
  float acc = bm1[t];
  for (int c = 0; c < 128; ++c) acc += gs[c] * Wm1[c * 64 + t];
  hs[t] = fmaxf(acc, 0.f);
  __syncthreads();
  if (t == 0) {
    float o = bm2[0];
    for (int j = 0; j < 64; ++j) o += hs[j] * Wm2[j];
    out[0] = o;
  }
}

// ---------------------------------------------------------------------------
extern "C" void kernel_launch(void* const* d_in, const int* in_sizes, int n_in,
                              void* d_out, int out_size, void* d_ws, size_t ws_size,
                              hipStream_t stream) {
  const float* x   = (const float*)d_in[0];
  const int*   ei  = (const int*)d_in[1];
  const float* W0  = (const float*)d_in[2];
  const float* as0 = (const float*)d_in[3];
  const float* ad0 = (const float*)d_in[4];
  const float* b0  = (const float*)d_in[5];
  const float* W1  = (const float*)d_in[6];
  const float* as1 = (const float*)d_in[7];
  const float* ad1 = (const float*)d_in[8];
  const float* b1  = (const float*)d_in[9];
  const float* W2  = (const float*)d_in[10];
  const float* as2 = (const float*)d_in[11];
  const float* ad2 = (const float*)d_in[12];
  const float* b2  = (const float*)d_in[13];
  const float* Wm1 = (const float*)d_in[14];
  const float* bm1 = (const float*)d_in[15];
  const float* Wm2 = (const float*)d_in[16];
  const float* bm2 = (const float*)d_in[17];

  const int N = in_sizes[0] / 128;     // 20000
  const int E = in_sizes[1] / 2;       // 320000
  const int ET = E + N;                // with self loops

  // workspace layout
  float*  Bb  = (float*)d_ws;               // N*512 fp32 (h between layers; h2 dest)
  ushort* xlb = (ushort*)(Bb + (size_t)N * 512);  // N*512 bf16 xl
  float*  asn = (float*)(xlb + (size_t)N * 512);  // N*4
  float*  adn = asn + (size_t)N * 4;        // N*4
  float*  g   = adn + (size_t)N * 4;        // 128 pool accumulator
  int* counts = (int*)(g + 128);            // N
  int* cursor = counts + N;                 // N
  int* offs   = cursor + N;                 // N+1
  int* srcs   = offs + N + 1;               // ET
  // transposed+split weights (ushort), 64B-aligned
  ushort* w0h = (ushort*)(((uintptr_t)(srcs + ET) + 63) & ~(uintptr_t)63);
  ushort* w0l = w0h + 512 * 128;
  ushort* w1h = w0l + 512 * 128;
  ushort* w1l = w1h + 512 * 512;
  ushort* w2h = w1l + 512 * 512;
  ushort* w2l = w2h + 128 * 512;

  // zero pool accumulator + counts + cursor (contiguous)
  hipMemsetAsync(g, 0, (size_t)(128 + 2 * N) * sizeof(int), stream);

  // weight transpose + split (one kernel)
  wsplit_all_kernel<<<(98304 + 255) / 256, 256, 0, stream>>>(
      W0, W1, W2, w0h, w0l, w1h, w1l, w2h, w2l);

  // CSR by dst
  int ebl = (ET + 255) / 256;
  count_kernel<<<ebl, 256, 0, stream>>>(ei, counts, E, N);
  scan_kernel<<<1, 1024, 0, stream>>>(counts, offs, N);
  scatter_kernel<<<ebl, 256, 0, stream>>>(ei, offs, cursor, srcs, E, N);

  int nwb = (N + 3) / 4;               // wave-per-node kernels: 4 waves/block
  dim3 gG01(4, (N + 63) / 64);         // N=512: 4 heads x 313 row-blocks
  dim3 gG2(1, (N + 63) / 64);          // N=128: 1 head

  // layer 0: x[N,128] @ W0 -> xlb (bf16) + stats
  gemm_mfma_kernel<<<gG01, 256, 0, stream>>>(x, w0h, w0l, xlb, as0, ad0, asn, adn,
                                             N, 128, 512, 4);
  agg_kernel<4, true><<<nwb, 256, 0, stream>>>(xlb, asn, adn, offs, srcs, b0, Bb, N);

  // layer 1: h0[N,512] @ W1 -> xlb + stats
  gemm_mfma_kernel<<<gG01, 256, 0, stream>>>(Bb, w1h, w1l, xlb, as1, ad1, asn, adn,
                                             N, 512, 512, 4);
  agg_kernel<4, true><<<nwb, 256, 0, stream>>>(xlb, asn, adn, offs, srcs, b1, Bb, N);

  // layer 2: h1[N,512] @ W2 -> xlb (N*128) + stats; agg writes h2 into Bb
  gemm_mfma_kernel<<<gG2, 256, 0, stream>>>(Bb, w2h, w2l, xlb, as2, ad2, asn, adn,
                                            N, 512, 128, 1);
  agg_kernel<1, false><<<nwb, 256, 0, stream>>>(xlb, asn, adn, offs, srcs, b2, Bb, N);

  // mean pool + MLP
  pool_kernel<<<128, 128, 0, stream>>>(Bb, g, N);
  mlp_kernel<<<1, 64, 0, stream>>>(g, Wm1, bm1, Wm2, bm2, (float*)d_out, 1.0f / (float)N);
}

// Round 5
// 401.259 us; speedup vs baseline: 1.7727x; 1.0508x over previous
//
#include <hip/hip_runtime.h>
#include <math.h>

// ---------------------------------------------------------------------------
// GAT pipeline (R5):
//   wsplit + CSR build (count -> 3-phase scan -> scatter)  [once per launch]
//   per layer: split-bf16 MFMA GEMM (fused attn stats, bf16 xl out)
//              -> wave-per-node online-softmax agg (8-batched bf16 gather)
//   mean pool -> 2-layer MLP -> scalar out
// R4 post-mortem: agg VALU 46% + HBM 44% -> latency-bound serial gather.
// R5: 8-wide load batching in gather; multi-block scan (old one = 1 CU).
// ---------------------------------------------------------------------------

typedef float f32x4 __attribute__((ext_vector_type(4)));
typedef short s16x8 __attribute__((ext_vector_type(8)));
typedef short s16x4 __attribute__((ext_vector_type(4)));

__device__ inline ushort f2bf(float f) {
  unsigned u = __float_as_uint(f);
  u += 0x7FFF + ((u >> 16) & 1);          // round-to-nearest-even
  return (ushort)(u >> 16);
}
__device__ inline float bf2f(ushort h) { return __uint_as_float((unsigned)h << 16); }

// ---------------- CSR build ----------------
__global__ void count_kernel(const int* __restrict__ ei, int* __restrict__ counts,
                             int E, int n) {
  int t = blockIdx.x * blockDim.x + threadIdx.x;
  if (t < E) {
    atomicAdd(&counts[ei[E + t]], 1);          // dst row of edge_index
  } else if (t < E + n) {
    atomicAdd(&counts[t - E], 1);              // self loop
  }
}

// phase 1: per-block (256) sums
__global__ void scan1_kernel(const int* __restrict__ counts, int* __restrict__ partials,
                             int n) {
  __shared__ int sd[4];
  int i = blockIdx.x * 256 + threadIdx.x;
  int v = (i < n) ? counts[i] : 0;
  for (int m = 32; m; m >>= 1) v += __shfl_xor(v, m);
  if ((threadIdx.x & 63) == 0) sd[threadIdx.x >> 6] = v;
  __syncthreads();
  if (threadIdx.x == 0) partials[blockIdx.x] = sd[0] + sd[1] + sd[2] + sd[3];
}

// phase 2: exclusive scan of partials (nb <= 1024), single small block
__global__ void scan2_kernel(int* __restrict__ partials, int nb) {
  __shared__ int sd[1024];
  int t = threadIdx.x;
  int v = (t < nb) ? partials[t] : 0;
  sd[t] = v;
  __syncthreads();
  for (int off = 1; off < 1024; off <<= 1) {
    int u = (t >= off) ? sd[t - off] : 0;
    __syncthreads();
    sd[t] += u;
    __syncthreads();
  }
  if (t < nb) partials[t] = sd[t] - v;
}

// phase 3: per-block exclusive scan + carry
__global__ void scan3_kernel(const int* __restrict__ counts, const int* __restrict__ partials,
                             int* __restrict__ offsets, int n) {
  __shared__ int sd[256];
  int i = blockIdx.x * 256 + threadIdx.x;
  int t = threadIdx.x;
  int v = (i < n) ? counts[i] : 0;
  sd[t] = v;
  __syncthreads();
  for (int off = 1; off < 256; off <<= 1) {
    int u = (t >= off) ? sd[t - off] : 0;
    __syncthreads();
    sd[t] += u;
    __syncthreads();
  }
  int carry = partials[blockIdx.x];
  if (i < n) {
    offsets[i] = carry + sd[t] - v;
    if (i == n - 1) offsets[n] = carry + sd[t];
  }
}

__global__ void scatter_kernel(const int* __restrict__ ei, const int* __restrict__ offsets,
                               int* __restrict__ cursor, int* __restrict__ srcs,
                               int E, int n) {
  int t = blockIdx.x * blockDim.x + threadIdx.x;
  int s, d;
  if (t < E)          { s = ei[t]; d = ei[E + t]; }
  else if (t < E + n) { s = t - E; d = s; }
  else return;
  int pos = offsets[d] + atomicAdd(&cursor[d], 1);
  srcs[pos] = s;
}

// ------- weight transpose + bf16 split for all 3 layers in one launch -------
__global__ void wsplit_all_kernel(
    const float* __restrict__ W0, const float* __restrict__ W1,
    const float* __restrict__ W2, ushort* __restrict__ w0h, ushort* __restrict__ w0l,
    ushort* __restrict__ w1h, ushort* __restrict__ w1l, ushort* __restrict__ w2h,
    ushort* __restrict__ w2l) {
  int idx = blockIdx.x * 256 + threadIdx.x;
  const float* W; ushort *th, *tl; int K, N;
  if (idx < 16384)      { W = W0; th = w0h; tl = w0l; K = 128; N = 512; }
  else if (idx < 81920) { idx -= 16384; W = W1; th = w1h; tl = w1l; K = 512; N = 512; }
  else if (idx < 98304) { idx -= 81920; W = W2; th = w2h; tl = w2l; K = 512; N = 128; }
  else return;
  int n = idx % N;
  int k4 = (idx / N) << 2;
  s16x4 hv, lv;
#pragma unroll
  for (int r = 0; r < 4; ++r) {
    float w = W[(size_t)(k4 + r) * N + n];
    ushort h = f2bf(w);
    hv[r] = (short)h;
    lv[r] = (short)f2bf(w - bf2f(h));
  }
  *(s16x4*)&th[(size_t)n * K + k4] = hv;
  *(s16x4*)&tl[(size_t)n * K + k4] = lv;
}

// ---------------- split-bf16 MFMA GEMM + fused per-head attn stats ----------
// Cb[M,N] (bf16) = A[M,K] @ B[K,N]; block col range = one head (128 cols).
// asn/adn[M,H] = per-row dot of fp32 accum with a_s/a_d[h,0:128] (exact).
// BM=64, BN=128, BK=32; 256 threads = 4 waves (2x2), 16x16x32 MFMA.
__global__ __launch_bounds__(256, 2) void gemm_mfma_kernel(
    const float* __restrict__ A, const ushort* __restrict__ Bth,
    const ushort* __restrict__ Btl, ushort* __restrict__ Cb,
    const float* __restrict__ a_s, const float* __restrict__ a_d,
    float* __restrict__ asn, float* __restrict__ adn,
    int M, int K, int N, int H) {
  __shared__ ushort Ash[64][40], Asl[64][40];
  __shared__ ushort Bsh[128][40], Bsl[128][40];
  __shared__ float st_sh[2][64][2];           // [src/dst][row][wave-col-half]
  int tid = threadIdx.x;
  int row0 = blockIdx.y * 64, col0 = blockIdx.x * 128;
  int hidx = blockIdx.x;                      // head index (N==H*128)
  int am = tid >> 2, ak = (tid & 3) << 3;     // A stage: row am, 8 k-vals
  int bn = tid >> 1, bk = (tid & 1) << 4;     // B stage: row bn, 16 k-vals
  int lane = tid & 63, wid = tid >> 6;
  int wm = (wid & 1) << 5, wn = (wid >> 1) << 6;
  int fr = lane & 15, fq = (lane >> 4) << 3;  // fragment row/col, k-offset
  f32x4 acc[2][4] = {};
  const float* Arow = A + (size_t)(row0 + am) * K;
  bool avalid = (row0 + am) < M;
  const ushort* bhp = Bth + (size_t)(col0 + bn) * K + bk;
  const ushort* blp = Btl + (size_t)(col0 + bn) * K + bk;

  for (int k0 = 0; k0 < K; k0 += 32) {
    // ---- stage A (fp32 -> hi/lo bf16) ----
    float v[8];
    if (avalid) {
      float4 t0 = *(const float4*)(Arow + k0 + ak);
      float4 t1 = *(const float4*)(Arow + k0 + ak + 4);
      v[0] = t0.x; v[1] = t0.y; v[2] = t0.z; v[3] = t0.w;
      v[4] = t1.x; v[5] = t1.y; v[6] = t1.z; v[7] = t1.w;
    } else {
#pragma unroll
      for (int r = 0; r < 8; ++r) v[r] = 0.f;
    }
    s16x8 hv, lv;
#pragma unroll
    for (int r = 0; r < 8; ++r) {
      ushort h = f2bf(v[r]);
      hv[r] = (short)h;
      lv[r] = (short)f2bf(v[r] - bf2f(h));
    }
    *(s16x8*)&Ash[am][ak] = hv;
    *(s16x8*)&Asl[am][ak] = lv;
    // ---- stage B (pre-split ushort copy) ----
    *(s16x8*)&Bsh[bn][bk]     = *(const s16x8*)(bhp + k0);
    *(s16x8*)&Bsh[bn][bk + 8] = *(const s16x8*)(bhp + k0 + 8);
    *(s16x8*)&Bsl[bn][bk]     = *(const s16x8*)(blp + k0);
    *(s16x8*)&Bsl[bn][bk + 8] = *(const s16x8*)(blp + k0 + 8);
    __syncthreads();
    // ---- fragments + MFMA (ah*bh + ah*bl + al*bh) ----
    s16x8 ah[2], al[2], bh[4], bl[4];
#pragma unroll
    for (int i = 0; i < 2; ++i) {
      ah[i] = *(const s16x8*)&Ash[wm + i * 16 + fr][fq];
      al[i] = *(const s16x8*)&Asl[wm + i * 16 + fr][fq];
    }
#pragma unroll
    for (int j = 0; j < 4; ++j) {
      bh[j] = *(const s16x8*)&Bsh[wn + j * 16 + fr][fq];
      bl[j] = *(const s16x8*)&Bsl[wn + j * 16 + fr][fq];
    }
#pragma unroll
    for (int i = 0; i < 2; ++i)
#pragma unroll
      for (int j = 0; j < 4; ++j) {
        acc[i][j] = __builtin_amdgcn_mfma_f32_16x16x32_bf16(ah[i], bh[j], acc[i][j], 0, 0, 0);
        acc[i][j] = __builtin_amdgcn_mfma_f32_16x16x32_bf16(ah[i], bl[j], acc[i][j], 0, 0, 0);
        acc[i][j] = __builtin_amdgcn_mfma_f32_16x16x32_bf16(al[i], bh[j], acc[i][j], 0, 0, 0);
      }
    __syncthreads();
  }
  // ---- epilogue: bf16 store + fused stats ----
  // C/D layout: col = lane&15 (fr), row = (lane>>4)*4 + reg
  float asv[4], adv[4];
#pragma unroll
  for (int j = 0; j < 4; ++j) {
    asv[j] = a_s[hidx * 128 + wn + j * 16 + fr];
    adv[j] = a_d[hidx * 128 + wn + j * 16 + fr];
  }
  int rb = row0 + wm + ((lane >> 4) << 2);
  int cb = col0 + wn + fr;
#pragma unroll
  for (int i = 0; i < 2; ++i)
#pragma unroll
    for (int r = 0; r < 4; ++r) {
      int row = rb + i * 16 + r;
      float sp = 0.f, dp = 0.f;
#pragma unroll
      for (int j = 0; j < 4; ++j) {
        float c = acc[i][j][r];
        sp += c * asv[j];
        dp += c * adv[j];
        if (row < M) Cb[(size_t)row * N + cb + j * 16] = f2bf(c);
      }
      // reduce over fr (16 lanes per row-group)
#pragma unroll
      for (int m = 1; m < 16; m <<= 1) {
        sp += __shfl_xor(sp, m);
        dp += __shfl_xor(dp, m);
      }
      if ((lane & 15) == 0) {
        int rowb = wm + i * 16 + ((lane >> 4) << 2) + r;
        st_sh[0][rowb][wid >> 1] = sp;
        st_sh[1][rowb][wid >> 1] = dp;
      }
    }
  __syncthreads();
  if (tid < 64) {
    int row = row0 + tid;
    if (row < M) {
      asn[(size_t)row * H + hidx] = st_sh[0][tid][0] + st_sh[0][tid][1];
      adn[(size_t)row * H + hidx] = st_sh[1][tid][0] + st_sh[1][tid][1];
    }
  }
}

// ------- wave-per-node online-softmax + 8-batched bf16 gather -------
template <int H, bool RELU>
__global__ __launch_bounds__(256) void agg_kernel(
    const ushort* __restrict__ xl, const float* __restrict__ asn,
    const float* __restrict__ adn, const int* __restrict__ offsets,
    const int* __restrict__ srcs, const float* __restrict__ bias,
    float* __restrict__ out, int n) {
  constexpr int C = 128;
  constexpr int HC = H * C;
  constexpr int CPL = HC / 64;        // channels per lane: 8 (H=4) or 2 (H=1)
  __shared__ float alpha_sh[4][64 * H];
  __shared__ int src_sh[4][64];
  int wib = threadIdx.x >> 6;
  int lane = threadIdx.x & 63;
  int nd = blockIdx.x * 4 + wib;
  if (nd >= n) return;
  int beg = offsets[nd];
  int deg = offsets[nd + 1] - beg;
  float adl[H];
#pragma unroll
  for (int h = 0; h < H; ++h) adl[h] = adn[nd * H + h];

  // single pass: per-lane online (m, l) per head
  float mh[H], lh[H];
#pragma unroll
  for (int h = 0; h < H; ++h) { mh[h] = -3.0e38f; lh[h] = 0.f; }
  for (int j0 = 0; j0 < deg; j0 += 64) {
    int j = j0 + lane;
    if (j < deg) {
      int s = srcs[beg + j];
      float ev[H];
      if constexpr (H == 4) {
        float4 av = *(const float4*)&asn[(size_t)s * 4];
        ev[0] = av.x; ev[1] = av.y; ev[2] = av.z; ev[3] = av.w;
      } else {
        ev[0] = asn[s];
      }
#pragma unroll
      for (int h = 0; h < H; ++h) {
        float e = ev[h] + adl[h];
        e = (e > 0.f) ? e : 0.2f * e;
        float mn = fmaxf(mh[h], e);
        lh[h] = lh[h] * __expf(mh[h] - mn) + __expf(e - mn);
        mh[h] = mn;
      }
    }
  }
  // butterfly merge of (m,l)
#pragma unroll
  for (int h = 0; h < H; ++h) {
    for (int m = 1; m < 64; m <<= 1) {
      float mo = __shfl_xor(mh[h], m);
      float lo = __shfl_xor(lh[h], m);
      float mn = fmaxf(mh[h], mo);
      lh[h] = lh[h] * __expf(mh[h] - mn) + lo * __expf(mo - mn);
      mh[h] = mn;
    }
    lh[h] = 1.f / lh[h];               // 1/den
  }

  // gather pass: out[nd] = sum_j alpha_j * xl[src_j]  (bf16 payload)
  float acc[CPL];
#pragma unroll
  for (int i = 0; i < CPL; ++i) acc[i] = 0.f;
  int ch0 = lane * CPL;
  int hm = ch0 / C;                    // my head
  for (int j0 = 0; j0 < deg; j0 += 64) {
    int j = j0 + lane;
    if (j < deg) {
      int s = srcs[beg + j];
      src_sh[wib][lane] = s;
      float ev[H];
      if constexpr (H == 4) {
        float4 av = *(const float4*)&asn[(size_t)s * 4];
        ev[0] = av.x; ev[1] = av.y; ev[2] = av.z; ev[3] = av.w;
      } else {
        ev[0] = asn[s];
      }
#pragma unroll
      for (int h = 0; h < H; ++h) {
        float e = ev[h] + adl[h];
        e = (e > 0.f) ? e : 0.2f * e;
        alpha_sh[wib][lane * H + h] = __expf(e - mh[h]) * lh[h];
      }
    }
    __builtin_amdgcn_wave_barrier();   // wave-lockstep LDS producer->consumer
    int cl = min(64, deg - j0);
    int jj = 0;
    if constexpr (CPL == 8) {
      for (; jj + 8 <= cl; jj += 8) {
        s16x8 v[8]; float a[8];
#pragma unroll
        for (int u = 0; u < 8; ++u) {
          int s = src_sh[wib][jj + u];
          a[u] = alpha_sh[wib][(jj + u) * H + hm];
          v[u] = *(const s16x8*)(xl + (size_t)s * HC + ch0);
        }
#pragma unroll
        for (int u = 0; u < 8; ++u)
#pragma unroll
          for (int i = 0; i < 8; ++i) acc[i] += a[u] * bf2f((ushort)v[u][i]);
      }
      for (; jj < cl; ++jj) {
        int s = src_sh[wib][jj];
        float a = alpha_sh[wib][jj * H + hm];
        s16x8 v = *(const s16x8*)(xl + (size_t)s * HC + ch0);
#pragma unroll
        for (int i = 0; i < 8; ++i) acc[i] += a * bf2f((ushort)v[i]);
      }
    } else {
      for (; jj + 8 <= cl; jj += 8) {
        uint v[8]; float a[8];
#pragma unroll
        for (int u = 0; u < 8; ++u) {
          int s = src_sh[wib][jj + u];
          a[u] = alpha_sh[wib][jj + u];
          v[u] = *(const uint*)(xl + (size_t)s * HC + ch0);
        }
#pragma unroll
        for (int u = 0; u < 8; ++u) {
          acc[0] += a[u] * bf2f((ushort)(v[u] & 0xFFFF));
          acc[1] += a[u] * bf2f((ushort)(v[u] >> 16));
        }
      }
      for (; jj < cl; ++jj) {
        int s = src_sh[wib][jj];
        float a = alpha_sh[wib][jj];
        uint v = *(const uint*)(xl + (size_t)s * HC + ch0);
        acc[0] += a * bf2f((ushort)(v & 0xFFFF));
        acc[1] += a * bf2f((ushort)(v >> 16));
      }
    }
    __builtin_amdgcn_wave_barrier();
  }
  float* op = out + (size_t)nd * HC + ch0;
#pragma unroll
  for (int i = 0; i < CPL; ++i) {
    float v = acc[i] + bias[ch0 + i];
    if (RELU) v = fmaxf(v, 0.f);
    op[i] = v;
  }
}

// ---------------- mean pool (partial sums + atomics) ----------------
__global__ void pool_kernel(const float* __restrict__ h, float* __restrict__ g, int n) {
  int c = threadIdx.x;                 // 128 threads
  float acc = 0.f;
  for (int r = blockIdx.x; r < n; r += gridDim.x) acc += h[(size_t)r * 128 + c];
  atomicAdd(&g[c], acc);
}

// ---------------- final MLP: relu(g/N @ Wm1 + bm1) @ Wm2 + bm2 ----------------
__global__ void mlp_kernel(const float* __restrict__ g, const float* __restrict__ Wm1,
                           const float* __restrict__ bm1, const float* __restrict__ Wm2,
                           const float* __restrict__ bm2, float* __restrict__ out,
                           float invn) {
  __shared__ float gs[128];
  __shared__ float hs[64];
  int t = threadIdx.x;                 // 64 threads
  gs[t] = g[t] * invn;
  gs[t + 64] = g[t + 64] * invn;
  __syncthreads();
  float acc = bm1[t];
  for (int c = 0; c < 128; ++c) acc += gs[c] * Wm1[c * 64 + t];
  hs[t] = fmaxf(acc, 0.f);
  __syncthreads();
  if (t == 0) {
    float o = bm2[0];
    for (int j = 0; j < 64; ++j) o += hs[j] * Wm2[j];
    out[0] = o;
  }
}

// ---------------------------------------------------------------------------
extern "C" void kernel_launch(void* const* d_in, const int* in_sizes, int n_in,
                              void* d_out, int out_size, void* d_ws, size_t ws_size,
                              hipStream_t stream) {
  const float* x   = (const float*)d_in[0];
  const int*   ei  = (const int*)d_in[1];
  const float* W0  = (const float*)d_in[2];
  const float* as0 = (const float*)d_in[3];
  const float* ad0 = (const float*)d_in[4];
  const float* b0  = (const float*)d_in[5];
  const float* W1  = (const float*)d_in[6];
  const float* as1 = (const float*)d_in[7];
  const float* ad1 = (const float*)d_in[8];
  const float* b1  = (const float*)d_in[9];
  const float* W2  = (const float*)d_in[10];
  const float* as2 = (const float*)d_in[11];
  const float* ad2 = (const float*)d_in[12];
  const float* b2  = (const float*)d_in[13];
  const float* Wm1 = (const float*)d_in[14];
  const float* bm1 = (const float*)d_in[15];
  const float* Wm2 = (const float*)d_in[16];
  const float* bm2 = (const float*)d_in[17];

  const int N = in_sizes[0] / 128;     // 20000
  const int E = in_sizes[1] / 2;       // 320000
  const int ET = E + N;                // with self loops

  // workspace layout
  float*  Bb  = (float*)d_ws;               // N*512 fp32 (h between layers; h2 dest)
  ushort* xlb = (ushort*)(Bb + (size_t)N * 512);  // N*512 bf16 xl
  float*  asn = (float*)(xlb + (size_t)N * 512);  // N*4
  float*  adn = asn + (size_t)N * 4;        // N*4
  float*  g   = adn + (size_t)N * 4;        // 128 pool accumulator
  int* counts = (int*)(g + 128);            // N
  int* cursor = counts + N;                 // N
  int* offs   = cursor + N;                 // N+1
  int* srcs   = offs + N + 1;               // ET
  int* parts  = srcs + ET;                  // ~128 scan partials
  // transposed+split weights (ushort), 64B-aligned
  ushort* w0h = (ushort*)(((uintptr_t)(parts + 1024) + 63) & ~(uintptr_t)63);
  ushort* w0l = w0h + 512 * 128;
  ushort* w1h = w0l + 512 * 128;
  ushort* w1l = w1h + 512 * 512;
  ushort* w2h = w1l + 512 * 512;
  ushort* w2l = w2h + 128 * 512;

  // zero pool accumulator + counts + cursor (contiguous)
  hipMemsetAsync(g, 0, (size_t)(128 + 2 * N) * sizeof(int), stream);

  // weight transpose + split (one kernel)
  wsplit_all_kernel<<<(98304 + 255) / 256, 256, 0, stream>>>(
      W0, W1, W2, w0h, w0l, w1h, w1l, w2h, w2l);

  // CSR by dst (multi-block scan)
  int ebl = (ET + 255) / 256;
  int nb = (N + 255) / 256;            // 79 scan blocks
  count_kernel<<<ebl, 256, 0, stream>>>(ei, counts, E, N);
  scan1_kernel<<<nb, 256, 0, stream>>>(counts, parts, N);
  scan2_kernel<<<1, 1024, 0, stream>>>(parts, nb);
  scan3_kernel<<<nb, 256, 0, stream>>>(counts, parts, offs, N);
  scatter_kernel<<<ebl, 256, 0, stream>>>(ei, offs, cursor, srcs, E, N);

  int nwb = (N + 3) / 4;               // wave-per-node kernels: 4 waves/block
  dim3 gG01(4, (N + 63) / 64);         // N=512: 4 heads x 313 row-blocks
  dim3 gG2(1, (N + 63) / 64);          // N=128: 1 head

  // layer 0: x[N,128] @ W0 -> xlb (bf16) + stats
  gemm_mfma_kernel<<<gG01, 256, 0, stream>>>(x, w0h, w0l, xlb, as0, ad0, asn, adn,
                                             N, 128, 512, 4);
  agg_kernel<4, true><<<nwb, 256, 0, stream>>>(xlb, asn, adn, offs, srcs, b0, Bb, N);

  // layer 1: h0[N,512] @ W1 -> xlb + stats
  gemm_mfma_kernel<<<gG01, 256, 0, stream>>>(Bb, w1h, w1l, xlb, as1, ad1, asn, adn,
                                             N, 512, 512, 4);
  agg_kernel<4, true><<<nwb, 256, 0, stream>>>(xlb, asn, adn, offs, srcs, b1, Bb, N);

  // layer 2: h1[N,512] @ W2 -> xlb (N*128) + stats; agg writes h2 into Bb
  gemm_mfma_kernel<<<gG2, 256, 0, stream>>>(Bb, w2h, w2l, xlb, as2, ad2, asn, adn,
                                            N, 512, 128, 1);
  agg_kernel<1, false><<<nwb, 256, 0, stream>>>(xlb, asn, adn, offs, srcs, b2, Bb, N);

  // mean pool + MLP
  pool_kernel<<<128, 128, 0, stream>>>(Bb, g, N);
  mlp_kernel<<<1, 64, 0, stream>>>(g, Wm1, bm1, Wm2, bm2, (float*)d_out, 1.0f / (float)N);
}